// Round 5
// baseline (1963.562 us; speedup 1.0000x reference)
//
#include <hip/hip_runtime.h>
#include <cstdio>
#include <cmath>
#include <cstdint>

// ---------------- problem constants ----------------
constexpr int BM = 512 * 104;       // 53248 rows
constexpr float BN_EPS = 1e-5f;

// ---------------- workspace layout (bytes) ----------------
constexpr size_t SZ_BF   = (size_t)BM * 512 * 2;           // 54,525,952
constexpr size_t SZ_MAT5 = (size_t)5 * 512 * 512 * 4;      // 5,242,880
constexpr size_t OFF_YB0 = 0;                              // conv ping buffer (bf16 raw y)
constexpr size_t OFF_YB1 = OFF_YB0 + SZ_BF;                // conv pong buffer
constexpr size_t OFF_WT2 = OFF_YB1 + SZ_BF;                // conv weights [4][3][co][ci] bf16
constexpr size_t OFF_X   = OFF_WT2 + 6291456;              // X=0.1A -> A2
constexpr size_t OFF_T1  = OFF_X   + SZ_MAT5;              // P -> A4
constexpr size_t OFF_T2  = OFF_T1  + SZ_MAT5;              // X2 -> A8
constexpr size_t OFF_E   = OFF_T2  + SZ_MAT5;              // E = expm(0.1A) - I
constexpr size_t OFF_MW  = OFF_E   + SZ_MAT5;              // S -> inv(S)  (GJ ping)
constexpr size_t OFF_P2  = OFF_MW  + SZ_MAT5;              // GJ pong, later A16
constexpr size_t OFF_P4  = OFF_P2  + SZ_MAT5;              // A32
constexpr size_t OFF_ROWT= OFF_P4  + SZ_MAT5;              // PIVI pong buffer
constexpr size_t OFF_COLS= OFF_ROWT + 655360;              // [5][512][64] ping
constexpr size_t OFF_COLS2=OFF_COLS + 655360;              // pong
constexpr size_t OFF_PIVI= OFF_COLS2 + 655360;             // [5][64][64] ping
constexpr size_t OFF_PJT = OFF_PIVI + 81920;               // proj_w^T
constexpr size_t OFF_F1T = OFF_PJT + 1048576;              // fc1_w^T
constexpr size_t OFF_G   = OFF_F1T + 1048576;              // g[b][h]
constexpr size_t OFF_POOL= OFF_G   + 1048576;              // pooled[b][o]
constexpr size_t OFF_Z   = OFF_POOL + 1048576;             // fc1 out
constexpr size_t OFF_ST  = OFF_Z   + 1048576;              // fp64 stats [6][2][512]
constexpr size_t OFF_U   = OFF_ST  + 49152;                // (unused)
constexpr size_t OFF_SV  = OFF_U   + 10240;                // (unused)
constexpr size_t OFF_V   = OFF_SV  + 10240;                // V[5][8][512]
constexpr size_t OFF_WV  = OFF_V   + 81920;                // W[5][13][512]
constexpr size_t OFF_S   = OFF_WV  + 133120;               // s[104] + sbar
constexpr size_t WS_NEED = OFF_S + 512;

// ---------------- bf16 helpers ----------------
__device__ __forceinline__ float bf2f(unsigned short u) {
    union { uint32_t i; float f; } x; x.i = (uint32_t)u << 16; return x.f;
}
__device__ __forceinline__ unsigned short f2bf(float f) {
    union { float f; uint32_t i; } x; x.f = f;
    uint32_t r = x.i + 0x7FFFu + ((x.i >> 16) & 1u);
    return (unsigned short)(r >> 16);
}

typedef __bf16 bf16x8 __attribute__((ext_vector_type(8)));
typedef float  f32x4  __attribute__((ext_vector_type(4)));

__device__ __forceinline__ void gld16(const void* g, void* l) {
    __builtin_amdgcn_global_load_lds((const __attribute__((address_space(1))) uint32_t*)g,
                                     (__attribute__((address_space(3))) uint32_t*)l, 16, 0, 0);
}

// BN+ReLU on a packed bf16 pair, repack via v_cvt_pk_bf16_f32 (RNE)
__device__ __forceinline__ uint32_t bnrelu_pk(uint32_t u, float sc0, float sc1, float sh0, float sh1) {
    union { uint32_t i; float f; } a, b;
    a.i = u << 16;            // lo element as f32
    b.i = u & 0xFFFF0000u;    // hi element as f32
    float x0 = fmaxf(fmaf(a.f, sc0, sh0), 0.0f);
    float x1 = fmaxf(fmaf(b.f, sc1, sh1), 0.0f);
    uint32_t r;
    asm volatile("v_cvt_pk_bf16_f32 %0, %1, %2" : "=v"(r) : "v"(x0), "v"(x1));
    return r;
}

// ============ merged: weight prepack + ZOH build + t512 + conv0 ============
__global__ void k_pre(const float* __restrict__ W, unsigned short* __restrict__ Wt2,
                      const float* __restrict__ Aall, float* __restrict__ X, float* __restrict__ MW,
                      float* __restrict__ COLSa, const float* __restrict__ Call, float* __restrict__ WV,
                      const float* __restrict__ pin0, float* __restrict__ pout0,
                      const float* __restrict__ pin1, float* __restrict__ pout1,
                      const float* __restrict__ xin, const float* __restrict__ w0,
                      const float* __restrict__ b0, unsigned short* __restrict__ y0,
                      double* __restrict__ s1g, double* __restrict__ s2g)
{
    __shared__ float tile[64 * 68];
    int bid = blockIdx.x;
    int tid = threadIdx.x;
    if (bid < 2048) {
        // conv weights -> bf16 [l][tap][co][ci], 16B-chunk XOR-swizzled per co row
        int co = bid & 511, l = bid >> 9;
        const float* src = W + (long)(l * 512 + co) * 512 * 3;
        unsigned short* dst = Wt2 + (long)l * 3 * 262144 + ((long)co << 9);
        int v = (co >> 1) & 3;
#pragma unroll
        for (int q = 0; q < 2; ++q) {
            int ci = tid * 2 + q;
            int chunk = (ci >> 3) & 3;
            int di = (ci & ~31) + (((chunk ^ v) & 3) << 3) + (ci & 7);
            float f0 = src[ci * 3 + 0], f1 = src[ci * 3 + 1], f2 = src[ci * 3 + 2];
            dst[di] = f2bf(f0);
            dst[262144 + di] = f2bf(f1);
            dst[524288 + di] = f2bf(f2);
        }
        return;
    }
    if (bid < 7168) {
        // ZOH build: X = 0.1*A, S = A + 0.001 I, COLS p=0, W0=C
        long i = (long)(bid - 2048) * 256 + tid;     // 5*262144 total
        float a = Aall[i];
        X[i] = 0.1f * a;
        int z = (int)(i >> 18);
        int rc = (int)(i & 262143);
        int r = rc >> 9, c = rc & 511;
        float mw = a + ((r == c) ? 0.001f : 0.0f);
        MW[i] = mw;
        if (c < 64) COLSa[(long)z * 32768 + r * 64 + c] = mw;
        if (i < 2560) WV[(i >> 9) * 6656 + (i & 511)] = Call[i];
        return;
    }
    if (bid < 7296) {
        // dual 512x512 transpose (proj_w, fc1_w)
        int id = bid - 7168;
        int bx = id & 7, by = (id >> 3) & 7, zi = id >> 6;
        const float* in = zi ? pin1 : pin0;
        float* outp = zi ? pout1 : pout0;
        for (int it = 0; it < 4; ++it) {
            int s = it * 256 + tid;
            int r = s >> 4, c4 = (s & 15) * 4;
            *(float4*)&tile[r * 68 + c4] = *(const float4*)&in[(long)(bx * 64 + r) * 512 + by * 64 + c4];
        }
        __syncthreads();
        for (int it = 0; it < 4; ++it) {
            int s = it * 256 + tid;
            int r = s >> 4, c4 = (s & 15) * 4;
            float4 v;
            v.x = tile[(c4 + 0) * 68 + r];
            v.y = tile[(c4 + 1) * 68 + r];
            v.z = tile[(c4 + 2) * 68 + r];
            v.w = tile[(c4 + 3) * 68 + r];
            *(float4*)&outp[(long)(by * 64 + r) * 512 + bx * 64 + c4] = v;
        }
        return;
    }
    {
        // conv0 (1->H) + stats, bf16 out
        int id = bid - 7296;
        int b = id & 511;
        int c = (id >> 9) * 256 + tid;
        float w_0 = w0[c * 3 + 0], w_1 = w0[c * 3 + 1], w_2 = w0[c * 3 + 2], bb = b0[c];
        const float* xb = xin + b * 104;
        unsigned short* yb = y0 + (long)b * 104 * 512 + c;
        float xm2 = 0.0f, xm1 = 0.0f;
        float s1 = 0.0f, s2 = 0.0f;
        for (int t = 0; t < 104; ++t) {
            float x0 = xb[t];
            float v = w_0 * xm2 + w_1 * xm1 + w_2 * x0 + bb;
            yb[t * 512] = f2bf(v);
            s1 += v; s2 += v * v;
            xm2 = xm1; xm1 = x0;
        }
        atomicAdd(&s1g[c], (double)s1);
        atomicAdd(&s2g[c], (double)s2);
    }
}

// ================= generic batched 64x64-tile fp32 matmul =================
// mode 0: C = acc
// mode 1: C = acc + 2*aux + I                  (A2 = E*E + 2E + I)
// mode 2: C = acc + aux                        (E = X2*P + X)
// mode 5: C = acc + aux[col]*aux2[0]
// mode 7: C = acc (=X2); Cp = 0.5I + aux/6 + acc/24
// mode 8: C = acc + aux[col]; fp64 column stats -> st1/st2
__global__ __launch_bounds__(256) void k_mm(
    const float* __restrict__ A, long sA, int lda,
    const float* __restrict__ Bm, long sB, int ldb,
    float* __restrict__ C, long sC, int ldc,
    int K, int mode,
    const float* __restrict__ aux, long sAux,
    const float* __restrict__ aux2, float* __restrict__ Cp,
    double* __restrict__ st1, double* __restrict__ st2, int pc)
{
    __shared__ float sm[2 * 32 * 68];
    float* As = sm;
    float* Bs = sm + 32 * 68;
    int z = blockIdx.z;
    A  += (long)z * sA;
    Bm += (long)z * sB;
    C  += (long)z * sC;
    if (aux) aux += (long)z * sAux;
    int m0 = blockIdx.x * 64, n0 = blockIdx.y * 64;
    int tid = threadIdx.x;
    int tx = tid & 15, ty = tid >> 4;
    float acc[4][4] = {};
    for (int k0 = 0; k0 < K; k0 += 32) {
        __syncthreads();
#pragma unroll
        for (int it = 0; it < 2; ++it) {
            int s = it * 256 + tid;
            int mm = s >> 3, k4 = (s & 7) * 4;
            float4 v = *(const float4*)&A[(long)(m0 + mm) * lda + k0 + k4];
            As[(k4 + 0) * 68 + mm] = v.x;
            As[(k4 + 1) * 68 + mm] = v.y;
            As[(k4 + 2) * 68 + mm] = v.z;
            As[(k4 + 3) * 68 + mm] = v.w;
        }
#pragma unroll
        for (int it = 0; it < 2; ++it) {
            int s = it * 256 + tid;
            int kk = s >> 4, n4 = (s & 15) * 4;
            *(float4*)&Bs[kk * 68 + n4] = *(const float4*)&Bm[(long)(k0 + kk) * ldb + n0 + n4];
        }
        __syncthreads();
#pragma unroll 8
        for (int kk = 0; kk < 32; ++kk) {
            float4 a = *(const float4*)&As[kk * 68 + ty * 4];
            float4 b = *(const float4*)&Bs[kk * 68 + tx * 4];
            float av[4] = {a.x, a.y, a.z, a.w};
            float bv[4] = {b.x, b.y, b.z, b.w};
#pragma unroll
            for (int i = 0; i < 4; ++i)
#pragma unroll
                for (int j = 0; j < 4; ++j)
                    acc[i][j] = fmaf(av[i], bv[j], acc[i][j]);
        }
    }
    float sc2 = (mode == 5) ? aux2[0] : 0.0f;
    float cs1[4] = {0, 0, 0, 0}, cs2[4] = {0, 0, 0, 0};
#pragma unroll
    for (int i = 0; i < 4; ++i) {
        int row = m0 + ty * 4 + i;
        int col0 = n0 + tx * 4;
        long base = (long)row * ldc + col0;
        float v[4];
#pragma unroll
        for (int j = 0; j < 4; ++j) v[j] = acc[i][j];
        if (mode == 1) {
            for (int j = 0; j < 4; ++j) {
                int col = col0 + j;
                v[j] = v[j] + 2.0f * aux[(long)row * 512 + col] + ((row == col) ? 1.0f : 0.0f);
            }
        } else if (mode == 2) {
            for (int j = 0; j < 4; ++j)
                v[j] = v[j] + aux[(long)row * 512 + col0 + j];
        } else if (mode == 5) {
            for (int j = 0; j < 4; ++j) v[j] += aux[col0 + j] * sc2;
        } else if (mode == 7) {
            float pv[4];
            for (int j = 0; j < 4; ++j) {
                int col = col0 + j;
                pv[j] = ((row == col) ? 0.5f : 0.0f) + aux[(long)row * 512 + col] * (1.0f / 6.0f)
                        + v[j] * (1.0f / 24.0f);
            }
            *(float4*)&Cp[base] = make_float4(pv[0], pv[1], pv[2], pv[3]);
        } else if (mode == 8) {
            for (int j = 0; j < 4; ++j) {
                v[j] += aux[col0 + j];
                cs1[j] += v[j]; cs2[j] += v[j] * v[j];
            }
        }
        *(float4*)&C[base] = make_float4(v[0], v[1], v[2], v[3]);
    }
    if (mode == 8) {
        __syncthreads();
        float* s1s = sm;           // [16][64]
        float* s2s = sm + 1024;
#pragma unroll
        for (int j = 0; j < 4; ++j) {
            s1s[ty * 64 + tx * 4 + j] = cs1[j];
            s2s[ty * 64 + tx * 4 + j] = cs2[j];
        }
        __syncthreads();
        if (tid < 64) {
            double a = 0.0, b = 0.0;
#pragma unroll
            for (int t = 0; t < 16; ++t) { a += s1s[t * 64 + tid]; b += s2s[t * 64 + tid]; }
            atomicAdd(&st1[n0 + tid], a);
            atomicAdd(&st2[n0 + tid], b);
        }
    }
}

// ====== fused GJ step + next-diag inverse.
// Per block: ROWT chunk (PIVI x MWin[pivot rows]) then elimination update
// (MWin -> MWout ping-pong). The block at (pcn,pcn) additionally runs the
// 64x64 pivoted GJ on its freshly computed diag tile and writes PIVN
// (double-buffered PIVI, so no dispatch-order race).
__global__ __launch_bounds__(256) void k_elim3(
    const float* __restrict__ MWin, float* __restrict__ MWout,
    const float* __restrict__ PIVI, float* __restrict__ PIVN,
    const float* __restrict__ COLSc, float* __restrict__ COLSn, int pc, int pcn)
{
    __shared__ float As[64 * 68];
    __shared__ float Rs[64 * 68];
    __shared__ float fv[64];
    __shared__ int perm[64];
    __shared__ int arr[64];
    __shared__ int pividx;
    __shared__ float dv;
    int z = blockIdx.z;
    MWin += (long)z * 262144; MWout += (long)z * 262144;
    PIVI += z * 4096; COLSc += (long)z * 32768; COLSn += (long)z * 32768;
    int m0 = blockIdx.x * 64, n0 = blockIdx.y * 64;
    int tid = threadIdx.x;
    int tx = tid & 15, ty = tid >> 4;

    // ---- phase 1: Rs = ROWT chunk for columns [n0, n0+64)
    if (n0 == pc) {
        for (int it = 0; it < 16; ++it) {
            int idx = it * 256 + tid;
            int r = idx >> 6, c = idx & 63;
            Rs[r * 68 + c] = PIVI[r * 64 + c];
        }
        __syncthreads();
    } else {
        {   // As[k*68 + r] = PIVI[r][k]; Rs[k*68 + c] = MWin[pc+k][n0+c]
            int m = tid >> 2, kb = (tid & 3) * 16;
#pragma unroll
            for (int u = 0; u < 4; ++u) {
                float4 v = *(const float4*)&PIVI[m * 64 + kb + u * 4];
                As[(kb + u * 4 + 0) * 68 + m] = v.x;
                As[(kb + u * 4 + 1) * 68 + m] = v.y;
                As[(kb + u * 4 + 2) * 68 + m] = v.z;
                As[(kb + u * 4 + 3) * 68 + m] = v.w;
            }
            int kr = tid >> 2, cb = (tid & 3) * 16;
#pragma unroll
            for (int u = 0; u < 4; ++u)
                *(float4*)&Rs[kr * 68 + cb + u * 4] =
                    *(const float4*)&MWin[(long)(pc + kr) * 512 + n0 + cb + u * 4];
        }
        __syncthreads();
        float acc1[4][4] = {};
#pragma unroll 8
        for (int kk = 0; kk < 64; ++kk) {
            float4 a = *(const float4*)&As[kk * 68 + ty * 4];
            float4 b = *(const float4*)&Rs[kk * 68 + tx * 4];
            float av[4] = {a.x, a.y, a.z, a.w};
            float bv[4] = {b.x, b.y, b.z, b.w};
#pragma unroll
            for (int i = 0; i < 4; ++i)
#pragma unroll
                for (int j = 0; j < 4; ++j)
                    acc1[i][j] = fmaf(av[i], bv[j], acc1[i][j]);
        }
        __syncthreads();   // all reads of Rs done
#pragma unroll
        for (int i = 0; i < 4; ++i)
#pragma unroll
            for (int j = 0; j < 4; ++j)
                Rs[(ty * 4 + i) * 68 + tx * 4 + j] = acc1[i][j];
        __syncthreads();
    }

    // ---- phase 2
    if (m0 == pc) {
        // pivot row-block: MWout = Rs
        for (int it = 0; it < 16; ++it) {
            int idx = it * 256 + tid;
            int r = idx >> 6, c = idx & 63;
            float v = Rs[r * 68 + c];
            MWout[(long)(pc + r) * 512 + n0 + c] = v;
            if (n0 == pcn) COLSn[(pc + r) * 64 + c] = v;
        }
        return;
    }
    {   // As[k*68 + m] = COLSc[m0+m][k]
        int m = tid >> 2, kb = (tid & 3) * 16;
#pragma unroll
        for (int u = 0; u < 4; ++u) {
            float4 v = *(const float4*)&COLSc[(m0 + m) * 64 + kb + u * 4];
            As[(kb + u * 4 + 0) * 68 + m] = v.x;
            As[(kb + u * 4 + 1) * 68 + m] = v.y;
            As[(kb + u * 4 + 2) * 68 + m] = v.z;
            As[(kb + u * 4 + 3) * 68 + m] = v.w;
        }
    }
    __syncthreads();
    float acc[4][4] = {};
#pragma unroll 8
    for (int kk = 0; kk < 64; ++kk) {
        float4 a = *(const float4*)&As[kk * 68 + ty * 4];
        float4 b = *(const float4*)&Rs[kk * 68 + tx * 4];
        float av[4] = {a.x, a.y, a.z, a.w};
        float bv[4] = {b.x, b.y, b.z, b.w};
#pragma unroll
        for (int i = 0; i < 4; ++i)
#pragma unroll
            for (int j = 0; j < 4; ++j)
                acc[i][j] = fmaf(av[i], bv[j], acc[i][j]);
    }
    bool inP = (n0 == pc);
    float vsav[4][4];
#pragma unroll
    for (int i = 0; i < 4; ++i) {
        int row = m0 + ty * 4 + i;
        int col0 = n0 + tx * 4;
        long base = (long)row * 512 + col0;
        float ov[4] = {0.f, 0.f, 0.f, 0.f};
        if (!inP) {
            float4 oldv = *(const float4*)&MWin[base];
            ov[0] = oldv.x; ov[1] = oldv.y; ov[2] = oldv.z; ov[3] = oldv.w;
        }
        float v[4];
#pragma unroll
        for (int j = 0; j < 4; ++j) { v[j] = ov[j] - acc[i][j]; vsav[i][j] = v[j]; }
        *(float4*)&MWout[base] = make_float4(v[0], v[1], v[2], v[3]);
        if (n0 == pcn)
            *(float4*)&COLSn[row * 64 + (col0 - pcn)] = make_float4(v[0], v[1], v[2], v[3]);
    }

    // ---- phase 3: next-step diag inverse (only the (pcn,pcn) block; skipped when pcn==512)
    if (!(m0 == pcn && n0 == pcn)) return;
    __syncthreads();                      // As free for reuse
    float* mat = As;                      // [64][65]
#pragma unroll
    for (int i = 0; i < 4; ++i)
#pragma unroll
        for (int j = 0; j < 4; ++j)
            mat[(ty * 4 + i) * 65 + tx * 4 + j] = vsav[i][j];
    __syncthreads();
    for (int j = 0; j < 64; ++j) {
        if (tid < 64) {
            float v = (tid >= j) ? fabsf(mat[tid * 65 + j]) : -1.0f;
            int idx = tid;
#pragma unroll
            for (int off = 32; off; off >>= 1) {
                float ov = __shfl_down(v, off);
                int oi = __shfl_down(idx, off);
                if (ov > v) { v = ov; idx = oi; }
            }
            if (tid == 0) pividx = idx;
        }
        __syncthreads();
        int r = pividx;
        if (tid < 64) {
            if (r != j) {
                float tj = mat[j * 65 + tid], tr = mat[r * 65 + tid];
                mat[j * 65 + tid] = tr; mat[r * 65 + tid] = tj;
            }
            if (tid == 0) perm[j] = r;
        }
        __syncthreads();
        if (tid < 64) {
            float piv = mat[j * 65 + j];
            float d = 1.0f / piv;
            fv[tid] = mat[tid * 65 + j];
            mat[j * 65 + tid] = (tid == j) ? d : mat[j * 65 + tid] * d;
            if (tid == 0) dv = d;
        }
        __syncthreads();
        {
            int i = tid & 63, c0 = (tid >> 6) * 16;
            if (i != j) {
                float f = fv[i];
                float dd = dv;
#pragma unroll
                for (int u = 0; u < 16; ++u) {
                    int c = c0 + u;
                    float val = mat[i * 65 + c] - f * mat[j * 65 + c];
                    if (c == j) val = -f * dd;
                    mat[i * 65 + c] = val;
                }
            }
        }
        __syncthreads();
    }
    if (tid == 0) {
        for (int c = 0; c < 64; ++c) arr[c] = c;
        for (int j = 63; j >= 0; --j) { int r = perm[j]; int t = arr[j]; arr[j] = arr[r]; arr[r] = t; }
    }
    __syncthreads();
    float* Pg = PIVN + z * 4096;
    for (int it = 0; it < 16; ++it) {
        int idx = it * 256 + tid;
        int r = idx >> 6, c = idx & 63;
        Pg[r * 64 + c] = mat[r * 65 + arr[c]];
    }
}

// ================= pivoted 64x64 Gauss-Jordan inverse in LDS (initial p=0) =================
__global__ __launch_bounds__(256) void k_inv64(const float* __restrict__ MW, int pblk, float* __restrict__ PIVI)
{
    __shared__ float mat[64 * 65];
    __shared__ float fv[64];
    __shared__ int perm[64];
    __shared__ int arr[64];
    __shared__ int pividx;
    __shared__ float dv;
    int z = blockIdx.x;
    const float* Mg = MW + (long)z * 262144 + (long)pblk * 64 * 512 + pblk * 64;
    int tid = threadIdx.x;
    for (int it = 0; it < 16; ++it) {
        int idx = it * 256 + tid;
        int r = idx >> 6, c = idx & 63;
        mat[r * 65 + c] = Mg[r * 512 + c];
    }
    __syncthreads();
    for (int j = 0; j < 64; ++j) {
        if (tid < 64) {
            float v = (tid >= j) ? fabsf(mat[tid * 65 + j]) : -1.0f;
            int idx = tid;
#pragma unroll
            for (int off = 32; off; off >>= 1) {
                float ov = __shfl_down(v, off);
                int oi = __shfl_down(idx, off);
                if (ov > v) { v = ov; idx = oi; }
            }
            if (tid == 0) pividx = idx;
        }
        __syncthreads();
        int r = pividx;
        if (tid < 64) {
            if (r != j) {
                float tj = mat[j * 65 + tid], tr = mat[r * 65 + tid];
                mat[j * 65 + tid] = tr; mat[r * 65 + tid] = tj;
            }
            if (tid == 0) perm[j] = r;
        }
        __syncthreads();
        if (tid < 64) {
            float piv = mat[j * 65 + j];
            float d = 1.0f / piv;
            fv[tid] = mat[tid * 65 + j];
            mat[j * 65 + tid] = (tid == j) ? d : mat[j * 65 + tid] * d;
            if (tid == 0) dv = d;
        }
        __syncthreads();
        {
            int i = tid & 63, c0 = (tid >> 6) * 16;
            if (i != j) {
                float f = fv[i];
                float dd = dv;
#pragma unroll
                for (int u = 0; u < 16; ++u) {
                    int c = c0 + u;
                    float val = mat[i * 65 + c] - f * mat[j * 65 + c];
                    if (c == j) val = -f * dd;
                    mat[i * 65 + c] = val;
                }
            }
        }
        __syncthreads();
    }
    if (tid == 0) {
        for (int c = 0; c < 64; ++c) arr[c] = c;
        for (int j = 63; j >= 0; --j) { int r = perm[j]; int t = arr[j]; arr[j] = arr[r]; arr[r] = t; }
    }
    __syncthreads();
    float* Pg = PIVI + z * 4096;
    for (int it = 0; it < 16; ++it) {
        int idx = it * 256 + tid;
        int r = idx >> 6, c = idx & 63;
        Pg[r * 64 + c] = mat[r * 65 + arr[c]];
    }
}

// ====== merged ZOH vector pipeline: bbar + V chain + W chain (per-z block) ======
__global__ __launch_bounds__(1024) void k_zoh(const char* __restrict__ ws,
                                              const float* __restrict__ Aall,
                                              const float* __restrict__ Ball)
{
    __shared__ float Vs[8][512];
    __shared__ float Ws[13][512];
    __shared__ float xs[512], us[512], sv[512];
    int z = blockIdx.x;
    const float* E   = (const float*)(ws + OFF_E)  + (long)z * 262144;
    const float* A2p = (const float*)(ws + OFF_X)  + (long)z * 262144;
    const float* A4p = (const float*)(ws + OFF_T1) + (long)z * 262144;
    const float* A8p = (const float*)(ws + OFF_T2) + (long)z * 262144;
    const float* A16p= (const float*)(ws + OFF_P2) + (long)z * 262144;
    const float* A32p= (const float*)(ws + OFF_P4) + (long)z * 262144;
    const float* Mi  = (const float*)(ws + OFF_MW) + (long)z * 262144;
    const float* Aa  = Aall + (long)z * 262144;
    float* Vg = (float*)(ws + OFF_V)  + (long)z * 4096;
    float* Wg = (float*)(ws + OFF_WV) + (long)z * 6656;
    int tid = threadIdx.x, lane = tid & 63, w = tid >> 6;   // 16 waves
    if (tid < 512) { xs[tid] = Ball[z * 512 + tid]; Ws[0][tid] = Wg[tid]; }
    __syncthreads();
    // ---- bbar: us = 0.1*(E x)
    for (int r = w * 32; r < w * 32 + 32; ++r) {
        const float* ar = E + (long)r * 512;
        double acc = 0.0;
#pragma unroll
        for (int m = 0; m < 8; ++m) acc += (double)ar[lane + m * 64] * (double)xs[lane + m * 64];
        for (int off = 32; off; off >>= 1) acc += __shfl_down(acc, off);
        if (lane == 0) us[r] = 0.1f * (float)acc;
    }
    __syncthreads();
    // vs = MW us  (stored in Vs[0])
    for (int r = w * 32; r < w * 32 + 32; ++r) {
        const float* ar = Mi + (long)r * 512;
        double acc = 0.0;
#pragma unroll
        for (int m = 0; m < 8; ++m) acc += (double)ar[lane + m * 64] * (double)us[lane + m * 64];
        for (int off = 32; off; off >>= 1) acc += __shfl_down(acc, off);
        if (lane == 0) Vs[0][r] = 1.0f * (float)acc;
    }
    __syncthreads();
    // sv = us - (A vs + 0.001 vs)
    for (int r = w * 32; r < w * 32 + 32; ++r) {
        const float* ar = Aa + (long)r * 512;
        double acc = 0.0;
#pragma unroll
        for (int m = 0; m < 8; ++m) acc += (double)ar[lane + m * 64] * (double)Vs[0][lane + m * 64];
        for (int off = 32; off; off >>= 1) acc += __shfl_down(acc, off);
        if (lane == 0) {
            float val = 1.0f * (float)acc + 0.001f * Vs[0][r];
            sv[r] = us[r] - val;
        }
    }
    __syncthreads();
    // V0 = vs + MW sv
    for (int r = w * 32; r < w * 32 + 32; ++r) {
        const float* ar = Mi + (long)r * 512;
        double acc = 0.0;
#pragma unroll
        for (int m = 0; m < 8; ++m) acc += (double)ar[lane + m * 64] * (double)sv[lane + m * 64];
        for (int off = 32; off; off >>= 1) acc += __shfl_down(acc, off);
        if (lane == 0) Vs[0][r] = Vs[0][r] + 1.0f * (float)acc;
    }
    __syncthreads();
    // ---- S1: V1 = E V0 + V0 (waves 0-7); W1 = A8^T W0 (waves 8-15)
    if (w < 8) {
        float xm[8];
#pragma unroll
        for (int m = 0; m < 8; ++m) xm[m] = Vs[0][lane + m * 64];
        for (int r = w * 64; r < w * 64 + 64; ++r) {
            const float* ar = E + (long)r * 512;
            double acc = 0.0;
#pragma unroll
            for (int m = 0; m < 8; ++m) acc += (double)ar[lane + m * 64] * (double)xm[m];
            for (int off = 32; off; off >>= 1) acc += __shfl_down(acc, off);
            if (lane == 0) Vs[1][r] = 1.0f * (float)acc + 1.0f * Vs[0][r];
        }
    } else {
        int c = tid - 512;
        double acc = 0.0;
#pragma unroll 8
        for (int j = 0; j < 512; ++j) acc += (double)A8p[(long)j * 512 + c] * (double)Ws[0][j];
        Ws[1][c] = (float)acc;
    }
    __syncthreads();
    // ---- S2: V2 = A2 V0, V3 = A2 V1; W2 = A16^T W0, W3 = A16^T W1
    if (w < 8) {
        const float* xv = (w < 4) ? Vs[0] : Vs[1];
        float* yv = (w < 4) ? Vs[2] : Vs[3];
        int r0 = (w & 3) * 128;
        float xm[8];
#pragma unroll
        for (int m = 0; m < 8; ++m) xm[m] = xv[lane + m * 64];
        for (int r = r0; r < r0 + 128; ++r) {
            const float* ar = A2p + (long)r * 512;
            double acc = 0.0;
#pragma unroll
            for (int m = 0; m < 8; ++m) acc += (double)ar[lane + m * 64] * (double)xm[m];
            for (int off = 32; off; off >>= 1) acc += __shfl_down(acc, off);
            if (lane == 0) yv[r] = (float)acc;
        }
    } else {
        const float* xv = (w < 12) ? Ws[0] : Ws[1];
        float* yv = (w < 12) ? Ws[2] : Ws[3];
        int q = (w < 12) ? (tid - 512) : (tid - 768);
        for (int u = 0; u < 2; ++u) {
            int c = q + u * 256;
            double acc = 0.0;
#pragma unroll 8
            for (int j = 0; j < 512; ++j) acc += (double)A16p[(long)j * 512 + c] * (double)xv[j];
            yv[c] = (float)acc;
        }
    }
    __syncthreads();
    // ---- S3: V4..7 = A4 V0..3; W4..7 = A32^T W0..3
    if (w < 8) {
        int t = w >> 1, r0 = (w & 1) * 256;
        float xm[8];
#pragma unroll
        for (int m = 0; m < 8; ++m) xm[m] = Vs[t][lane + m * 64];
        for (int r = r0; r < r0 + 256; ++r) {
            const float* ar = A4p + (long)r * 512;
            double acc = 0.0;
#pragma unroll
            for (int m = 0; m < 8; ++m) acc += (double)ar[lane + m * 64] * (double)xm[m];
            for (int off = 32; off; off >>= 1) acc += __shfl_down(acc, off);
            if (lane == 0) Vs[4 + t][r] = (float)acc;
        }
    } else {
        int c = tid - 512;
        double a0 = 0.0, a1 = 0.0, a2 = 0.0, a3 = 0.0;
#pragma unroll 8
        for (int j = 0; j < 512; ++j) {
            double a = (double)A32p[(long)j * 512 + c];
            a0 += a * (double)Ws[0][j]; a1 += a * (double)Ws[1][j];
            a2 += a * (double)Ws[2][j]; a3 += a * (double)Ws[3][j];
        }
        Ws[4][c] = (float)a0; Ws[5][c] = (float)a1; Ws[6][c] = (float)a2; Ws[7][c] = (float)a3;
    }
    __syncthreads();
    // ---- S4: W8..11 = A32^T W4..7
    if (tid < 512) {
        int c = tid;
        double a0 = 0.0, a1 = 0.0, a2 = 0.0, a3 = 0.0;
#pragma unroll 8
        for (int j = 0; j < 512; ++j) {
            double a = (double)A32p[(long)j * 512 + c];
            a0 += a * (double)Ws[4][j]; a1 += a * (double)Ws[5][j];
            a2 += a * (double)Ws[6][j]; a3 += a * (double)Ws[7][j];
        }
        Ws[8][c] = (float)a0; Ws[9][c] = (float)a1; Ws[10][c] = (float)a2; Ws[11][c] = (float)a3;
    }
    __syncthreads();
    // ---- S5: W12 = A32^T W8
    if (tid < 512) {
        double acc = 0.0;
#pragma unroll 8
        for (int j = 0; j < 512; ++j) acc += (double)A32p[(long)j * 512 + tid] * (double)Ws[8][j];
        Ws[12][tid] = (float)acc;
    }
    __syncthreads();
    // ---- write out
    for (int idx = tid; idx < 8 * 512; idx += 1024) Vg[idx] = ((float*)Vs)[idx];
    for (int idx = tid; idx < 13 * 512; idx += 1024) Wg[idx] = ((float*)Ws)[idx];
}

// ================= MFMA conv GEMM, 128x256 tile, tap-fused, BN+ReLU fused on A staging ====
// Extra block (blockIdx.x==416, y==0, l==1 only) runs the terms+s-kernel (free under convm).
__global__ __launch_bounds__(256, 2) void k_convm(
    const unsigned short* __restrict__ act,      // raw y of previous layer
    const unsigned short* __restrict__ Wt2,      // layer base [3][512][512] (chunk-swizzled)
    const float* __restrict__ bias,
    const double* __restrict__ STin,             // prev layer stats [2][512]
    const float* __restrict__ gam, const float* __restrict__ bet,
    unsigned short* __restrict__ yout,
    double* __restrict__ s1g, double* __restrict__ s2g,
    const float* __restrict__ WVt, const float* __restrict__ Vt, float* __restrict__ SVECt)
{
    __shared__ __align__(16) unsigned short As[130 * 32];     // 8320 B
    __shared__ __align__(16) unsigned short Bs[3 * 256 * 32]; // 49152 B
    __shared__ float SCs[512];
    __shared__ float SHs[512];
    __shared__ float invk[5];
    __shared__ float redk[2];
    int tid = threadIdx.x;
    if (blockIdx.x == 416) {
        if (blockIdx.y != 0 || WVt == nullptr) return;
        // ---- terms + s-kernel (256-thread variant, arithmetic identical per element)
        float* tl = (float*)As;
        for (int t = tid; t < 520; t += 256) {
            int z = t / 104, d = t - z * 104;
            int j = d >> 3, i = d & 7;
            const float* wp = WVt + z * 6656 + j * 512;
            const float* vp = Vt + z * 4096 + i * 512;
            float acc = 0.0f;
#pragma unroll 8
            for (int k = 0; k < 512; ++k) acc += wp[k] * vp[k];
            tl[t] = acc;
        }
        __syncthreads();
        int lane = tid & 63;
        for (int g = tid >> 6; g < 5; g += 4) {
            float a = tl[g * 104 + lane]; a = a * a;
            if (lane < 40) { float b = tl[g * 104 + 64 + lane]; a += b * b; }
#pragma unroll
            for (int off = 32; off; off >>= 1) a += __shfl_down(a, off);
            if (lane == 0) invk[g] = 1.0f / (sqrtf(a) + 1e-6f);
        }
        __syncthreads();
        float s = 0.0f;
        if (tid < 104) {
            s = 1.0f;
            for (int l = 0; l < 5; ++l) s *= tl[l * 104 + (103 - tid)] * invk[l];
            SVECt[tid] = s;
        }
        if (tid < 128) {
            float v = (tid < 104) ? s : 0.0f;
#pragma unroll
            for (int off = 32; off; off >>= 1) v += __shfl_down(v, off);
            if ((tid & 63) == 0) redk[tid >> 6] = v;
        }
        __syncthreads();
        if (tid == 0) SVECt[104] = (redk[0] + redk[1]) * (1.0f / 104.0f);
        return;
    }
    int m0 = blockIdx.x * 128, co0 = blockIdx.y * 256;
    int w = tid >> 6, lane = tid & 63;
    int wr = (w >> 1) * 64, wc = (w & 1) * 128;
    int fr = lane & 15, quad = lane >> 4;

    // BN scale/shift tables (fp64 stats -> f32)
    const double invN = 1.0 / (double)BM;
    for (int c = tid; c < 512; c += 256) {
        double mn = STin[c] * invN;
        double var = STin[512 + c] * invN - mn * mn;
        double rs = 1.0 / sqrt(var + (double)BN_EPS);
        double scd = (double)gam[c] * rs;
        SCs[c] = (float)scd;
        SHs[c] = (float)((double)bet[c] - mn * scd);
    }

    bool valid[4][3];
#pragma unroll
    for (int i = 0; i < 4; ++i) {
        int R = m0 + wr + i * 16 + fr;
        int t = R % 104;
#pragma unroll
        for (int tau = 0; tau < 3; ++tau) valid[i][tau] = (t + tau >= 2);
    }

    // precomputed swizzled LDS fragment addresses (ushort indices)
    int aoff[4][3];
#pragma unroll
    for (int i = 0; i < 4; ++i)
#pragma unroll
        for (int tau = 0; tau < 3; ++tau) {
            int r = wr + i * 16 + fr + tau;
            aoff[i][tau] = r * 32 + (((quad ^ (r >> 1)) & 3) << 3);
        }
    int boff[8];
#pragma unroll
    for (int j = 0; j < 8; ++j) {
        int rb = wc + j * 16 + fr;
        boff[j] = rb * 32 + (((quad ^ (rb >> 1)) & 3) << 3);
    }

    // A staging pointers (rows m0-2 .. m0+129 of act)
    int ka = (tid & 3) * 8;
    int g0 = m0 - 2 + (tid >> 2); if (g0 < 0) g0 = 0;
    int g1 = m0 + 62 + (tid >> 2);
    int g2 = m0 + 126 + (tid >> 2);
    const unsigned short* pa0 = act + (long)g0 * 512 + ka;
    const unsigned short* pa1 = act + (long)g1 * 512 + ka;
    const unsigned short* pa2 = act + (long)g2 * 512 + ka;
    // A staging write base (same chunk-XOR swizzle; (row>>1)&3 invariant across reps)
    int wbase = (tid >> 2) * 32 + ((((tid & 3) ^ (tid >> 3)) & 3) << 3);
    // B staging global base (swizzle baked into Wt2 by k_pre)
    const unsigned short* pbB = Wt2 + ((long)(co0 + (tid >> 2)) << 9) + ka;

    f32x4 zero4 = {0.f, 0.f, 0.f, 0.f};
    f32x4 acc[4][8];
#pragma unroll
    for (int i = 0; i < 4; ++i)
#pragma unroll
        for (int j = 0; j < 8; ++j) acc[i][j] = zero4;
    bf16x8 zer = {0, 0, 0, 0, 0, 0, 0, 0};

#pragma unroll 1
    for (int s = 0; s < 16; ++s) {
        int ci0 = s * 32;
        __syncthreads();
        // A: issue VGPR loads first (compiler can wait vmcnt(12), not 0)
        uint4 va0 = *(const uint4*)(pa0 + ci0);
        uint4 va1 = *(const uint4*)(pa1 + ci0);
        uint4 va2;
        if (tid < 8) va2 = *(const uint4*)(pa2 + ci0);
        // B: 12 async global->LDS (48 KB)
#pragma unroll
        for (int tau = 0; tau < 3; ++tau)
#pragma unroll
            for (int it = 0; it < 4; ++it)
                gld16(pbB + tau * 262144 + it * 32768 + ci0, &Bs[(tau * 4 + it) * 2048 + tid * 8]);
        // A: BN+ReLU + cvt_pk repack + swizzled ds_write
        int cb = ci0 + ka;
        float4 s0 = *(const float4*)&SCs[cb], s1v = *(const float4*)&SCs[cb + 4];
        float4 h0 = *(const float4*)&SHs[cb], h1v = *(const float4*)&SHs[cb + 4];
        {
            uint4 pk;
            pk.x = bnrelu_pk(va0.x, s0.x, s0.y, h0.x, h0.y);
            pk.y = bnrelu_pk(va0.y, s0.z, s0.w, h0.z, h0.w);
            pk.z = bnrelu_pk(va0.z, s1v.x, s1v.y, h1v.x, h1v.y);
            pk.w = bnrelu_pk(va0.w, s1v.z, s1v.w, h1v.z, h1v.w);
            *(uint4*)&As[wbase] = pk;
            pk.x = bnrelu_pk(va1.x, s0.x, s0.y, h0.x, h0.y);
            pk.y = bnrelu_pk(va1.y, s0.z, s0.w, h0.z, h0.w);
            pk.z = bnrelu_pk(va1.z, s1v.x, s1v.y, h1v.x, h1v.y);
            pk.w = bnrelu_pk(va1.w, s1v.z, s1v.w, h1v.z, h1v.w);
            *(uint4*)&As[wbase + 2048] = pk;
            if (tid < 8) {
                pk.x = bnrelu_pk(va2.x, s0.x, s0.y, h0.x, h0.y);
                pk.y = bnrelu_pk(va2.y, s0.z, s0.w, h0.z, h0.w);
                pk.z = bnrelu_pk(va2.z, s1v.x, s1v.y, h1v.x, h1v.y);
                pk.w = bnrelu_pk(va2.w, s1v.z, s1v.w, h1v.z, h1v.w);
                *(uint4*)&As[wbase + 4096] = pk;
            }
        }
        __syncthreads();
#pragma unroll
        for (int tau = 0; tau < 3; ++tau) {
            bf16x8 af[4];
#pragma unroll
            for (int i = 0; i < 4; ++i) {
                bf16x8 raw = *(const bf16x8*)&As[aoff[i][tau]];
                af[i] = valid[i][tau] ? raw : zer;
            }
            bf16x8 bfr[8];
#pragma unroll
            for (int j = 0; j < 8; ++j)
                bfr[j] = *(const bf16x8*)&Bs[tau * 8192 + boff[j]];
#pragma unroll
            for (int i = 0; i < 4; ++i)
#pragma unroll
                for (int j = 0; j < 8; ++j)
                    acc[i][j] = __builtin_amdgcn_mfma_f32_16x16x32_bf16(af[i], bfr[j], acc[i][j], 0, 0, 0);
        }
    }
    // epilogue: bias, bf16 store, per-channel stats
    float bcol[8], s1[8], s2[8];
#pragma unroll
    for (int jt = 0; jt < 8; ++jt) {
        bcol[jt] = bias[co0 + wc + jt * 16 + fr];
        s1[jt] = 0.0f; s2[jt] = 0.0f;
    }
#pragma unroll
    for (int i = 0; i < 4; ++i) {
        int rbase = m0 + wr + i * 16 + quad * 4;
#pragma unroll
        for (int jt = 0; jt < 8; ++jt) {
            int col = co0 + wc + jt * 16 + fr;
#pragma unroll
            for (int r = 0; r < 4; ++r) {
                float v = acc[i][jt][r] + bcol[jt];
                yout[(long)(rbase + r) * 512 + col] = f2bf(v);
                s1[jt] += v; s2[jt] += v * v;
            }
        }
    }
#pragma unroll
    for (int jt = 0; jt < 8; ++jt) {
        s1[jt] += __shfl_xor(s1[jt], 16); s1[jt] += __shfl_xor(s1[jt], 32);
        s2[jt] += __shfl_xor(s2[jt], 16); s2[jt] += __shfl_xor(s2[jt], 32);
    }
    __syncthreads();
    float* st = (float*)As;   // [4][128] x2 = 4 KB
    if (lane < 16) {
#pragma unroll
        for (int jt = 0; jt < 8; ++jt) {
            st[w * 128 + jt * 16 + lane] = s1[jt];
            st[512 + w * 128 + jt * 16 + lane] = s2[jt];
        }
    }
    __syncthreads();
    {
        int half = tid >> 7, cl = tid & 127;
        float a = st[half * 128 + cl] + st[(half + 2) * 128 + cl];
        float b = st[512 + half * 128 + cl] + st[512 + (half + 2) * 128 + cl];
        atomicAdd(&s1g[co0 + tid], (double)a);
        atomicAdd(&s2g[co0 + tid], (double)b);
    }
}

// ================= pool: g[b][h] = (1/M) sum_t s[t]*(relu(bn4(y4)) + pe[t][h]) =================
__global__ void k_pool(const unsigned short* __restrict__ y4, const double* __restrict__ ST4,
                       const float* __restrict__ gam, const float* __restrict__ bet,
                       const float* __restrict__ svec, float* __restrict__ g)
{
    __shared__ float sl[104];
    int b = blockIdx.x;
    int c = blockIdx.y * 256 + threadIdx.x;
    if (threadIdx.x < 104) sl[threadIdx.x] = svec[threadIdx.x];
    __syncthreads();
    const double invN = 1.0 / (double)BM;
    double mn = ST4[c] * invN;
    double var = ST4[512 + c] * invN - mn * mn;
    double rs = 1.0 / sqrt(var + (double)BN_EPS);
    double scd = (double)gam[c] * rs;
    float sc = (float)scd, sh = (float)((double)bet[c] - mn * scd);
    int he = c & ~1;
    float div = expf((float)he * (-0.017988946039015984f));   // -ln(10000)/512
    float acc = 0.0f;
    const unsigned short* yb = y4 + (long)b * 104 * 512 + c;
    for (int t = 0; t < 104; ++t) {
        float v = bf2f(yb[t * 512]);
        float hn = fmaxf(fmaf(v, sc, sh), 0.0f);
        float arg = (float)t * div;
        float pe = (c & 1) ? cosf(arg) : sinf(arg);
        acc += sl[t] * (hn + pe);
    }
    g[(long)b * 512 + c] = acc * (1.0f / 104.0f);
}

// BN(batch) -> exact GELU -> fc2
__global__ __launch_bounds__(256) void k_final(const float* __restrict__ zin, const double* __restrict__ st,
                                               const float* __restrict__ gam, const float* __restrict__ bet,
                                               const float* __restrict__ w2, const float* __restrict__ b2,
                                               float* __restrict__ outp)
{
    __shared__ float red[256];
    int b = blockIdx.x, tid = threadIdx.x;
    int oo[2] = { tid, tid + 256 };
    float gv[2];
#pragma unroll
    for (int q = 0; q < 2; ++q) {
        int o = oo[q];
        double m = st[o] * (1.0 / 512.0);
        double var = st[512 + o] * (1.0 / 512.0) - m * m;
        double rs = 1.0 / sqrt(var + (double)BN_EPS);
        float xn = (float)(((double)zin[(long)b * 512 + o] - m) * rs * (double)gam[o] + (double)bet[o]);
        gv[q] = 0.5f * xn * (1.0f + erff(xn * 0.70710678118654752f));
    }
    for (int n = 0; n < 5; ++n) {
        float p = gv[0] * w2[n * 512 + oo[0]] + gv[1] * w2[n * 512 + oo[1]];
        red[tid] = p;
        __syncthreads();
        for (int off = 128; off; off >>= 1) { if (tid < off) red[tid] += red[tid + off]; __syncthreads(); }
        if (tid == 0) outp[b * 5 + n] = red[0] + b2[n];
        __syncthreads();
    }
}

// ===================== host side =====================
static void mm(hipStream_t s, int Mt, int Nt, int z,
               const float* A, long sA, int lda,
               const float* B, long sB, int ldb,
               float* C, long sC, int ldc,
               int K, int mode,
               const float* aux = nullptr, long sAux = 0, const float* aux2 = nullptr,
               float* Cp = nullptr, double* st1 = nullptr, double* st2 = nullptr, int pc = 0)
{
    dim3 g(Mt, Nt, z);
    k_mm<<<g, 256, 0, s>>>(A, sA, lda, B, sB, ldb, C, sC, ldc, K, mode, aux, sAux, aux2, Cp, st1, st2, pc);
}

extern "C" void kernel_launch(void* const* d_in, const int* in_sizes, int n_in,
                              void* d_out, int out_size, void* d_ws, size_t ws_size,
                              hipStream_t stream)
{
    (void)in_sizes; (void)n_in; (void)out_size;
    const float* x       = (const float*)d_in[0];
    const float* conv_w0 = (const float*)d_in[1];
    const float* conv_b0 = (const float*)d_in[2];
    const float* conv_w  = (const float*)d_in[3];
    const float* conv_b  = (const float*)d_in[4];
    const float* bn_g    = (const float*)d_in[5];
    const float* bn_b    = (const float*)d_in[6];
    const float* proj_w  = (const float*)d_in[7];
    const float* proj_b  = (const float*)d_in[8];
    const float* A_all   = (const float*)d_in[9];
    const float* B_all   = (const float*)d_in[10];
    const float* C_all   = (const float*)d_in[11];
    const float* fc1_w   = (const float*)d_in[12];
    const float* fc1_b   = (const float*)d_in[13];
    const float* fbn_g   = (const float*)d_in[14];
    const float* fbn_b   = (const float*)d_in[15];
    const float* fc2_w   = (const float*)d_in[16];
    const float* fc2_b   = (const float*)d_in[17];
    float* outp = (float*)d_out;
    char* ws = (char*)d_ws;
    if (ws_size < WS_NEED) { printf("ws too small: %zu < %zu\n", ws_size, WS_NEED); return; }

    unsigned short* YB0 = (unsigned short*)(ws + OFF_YB0);
    unsigned short* YB1 = (unsigned short*)(ws + OFF_YB1);
    unsigned short* WT2 = (unsigned short*)(ws + OFF_WT2);
    float* Xb   = (float*)(ws + OFF_X);
    float* T1   = (float*)(ws + OFF_T1);
    float* T2   = (float*)(ws + OFF_T2);
    float* Eb   = (float*)(ws + OFF_E);
    float* MW   = (float*)(ws + OFF_MW);
    float* P2   = (float*)(ws + OFF_P2);
    float* P4   = (float*)(ws + OFF_P4);
    float* COLS1= (float*)(ws + OFF_COLS);
    float* COLS2= (float*)(ws + OFF_COLS2);
    float* PIVA = (float*)(ws + OFF_PIVI);
    float* PIVB = (float*)(ws + OFF_ROWT);
    float* PJT  = (float*)(ws + OFF_PJT);
    float* F1T  = (float*)(ws + OFF_F1T);
    float* G    = (float*)(ws + OFF_G);
    float* POOL = (float*)(ws + OFF_POOL);
    float* Zb   = (float*)(ws + OFF_Z);
    double* ST  = (double*)(ws + OFF_ST);
    float* V    = (float*)(ws + OFF_V);
    float* WV   = (float*)(ws + OFF_WV);
    float* SVEC = (float*)(ws + OFF_S);

    const long SM = 262144;
    hipMemsetAsync(ws + OFF_ST, 0, 49152, stream);

    // ---- merged prepack + build + t512 + conv0 ----
    k_pre<<<8320, 256, 0, stream>>>(conv_w, WT2, A_all, Xb, MW, COLS1, C_all, WV,
                                    proj_w, PJT, fc1_w, F1T,
                                    x, conv_w0, conv_b0, YB0, ST, ST + 512);

    // ---- blocked Gauss-Jordan inverse of S (MW<->P2 ping-pong; PIVI double-buffered) ----
    {
        float* MB[2]  = { MW, P2 };
        float* PB[2]  = { PIVA, PIVB };
        k_inv64<<<5, 256, 0, stream>>>(MW, 0, PB[0]);
        for (int p = 0; p < 8; ++p) {
            int pc = p * 64;
            float* Cc = (p & 1) ? COLS2 : COLS1;
            float* Cn = (p & 1) ? COLS1 : COLS2;
            k_elim3<<<dim3(8, 8, 5), 256, 0, stream>>>(MB[p & 1], MB[(p + 1) & 1],
                                                       PB[p & 1], PB[(p + 1) & 1],
                                                       Cc, Cn, pc, pc + 64);
        }
    }
    // ---- expm chain: X2(+P), E, A2, A4, A8, A16, A32 ----
    mm(stream, 8, 8, 5, Xb, SM, 512, Xb, SM, 512, T2, SM, 512, 512, 7, Xb, SM, nullptr, T1);
    mm(stream, 8, 8, 5, T2, SM, 512, T1, SM, 512, Eb, SM, 512, 512, 2, Xb, SM);
    mm(stream, 8, 8, 5, Eb, SM, 512, Eb, SM, 512, Xb, SM, 512, 512, 1, Eb, SM);
    mm(stream, 8, 8, 5, Xb, SM, 512, Xb, SM, 512, T1, SM, 512, 512, 0);
    mm(stream, 8, 8, 5, T1, SM, 512, T1, SM, 512, T2, SM, 512, 512, 0);
    mm(stream, 8, 8, 5, T2, SM, 512, T2, SM, 512, P2, SM, 512, 512, 0);
    mm(stream, 8, 8, 5, P2, SM, 512, P2, SM, 512, P4, SM, 512, 512, 0);
    // ---- merged bbar + V/W chains ----
    k_zoh<<<5, 1024, 0, stream>>>(ws, A_all, B_all);

    // ---- conv chain (termsk rides as extra block in l=1) ----
    for (int l = 1; l <= 4; ++l) {
        unsigned short* inb  = (l & 1) ? YB0 : YB1;
        unsigned short* outb = (l & 1) ? YB1 : YB0;
        dim3 grid(l == 1 ? 417 : 416, 2);
        k_convm<<<grid, 256, 0, stream>>>(inb, WT2 + (size_t)(l - 1) * 3 * 262144,
                                          conv_b + (l - 1) * 512,
                                          ST + (l - 1) * 1024, bn_g + (l - 1) * 512, bn_b + (l - 1) * 512,
                                          outb, ST + l * 1024, ST + l * 1024 + 512,
                                          (l == 1) ? WV : nullptr, V, SVEC);
    }
    k_pool<<<dim3(512, 2), 256, 0, stream>>>(YB0, ST + 4 * 1024, bn_g + 4 * 512, bn_b + 4 * 512, SVEC, G);

    // ---- head ----
    mm(stream, 8, 8, 1, G, 0, 512, PJT, 0, 512, POOL, 0, 512, 512, 5, proj_b, 0, SVEC + 104);
    mm(stream, 8, 8, 1, POOL, 0, 512, F1T, 0, 512, Zb, 0, 512, 512, 8, fc1_b, 0, nullptr, nullptr,
       ST + 5 * 1024, ST + 5 * 1024 + 512);
    k_final<<<512, 256, 0, stream>>>(Zb, ST + 5 * 1024, fbn_g, fbn_b, fc2_w, fc2_b, outp);
}

// Round 6
// 1711.838 us; speedup vs baseline: 1.1470x; 1.1470x over previous
//
#include <hip/hip_runtime.h>
#include <cstdio>
#include <cmath>
#include <cstdint>

// ---------------- problem constants ----------------
constexpr int BM = 512 * 104;       // 53248 rows
constexpr float BN_EPS = 1e-5f;

// ---------------- workspace layout (bytes) ----------------
constexpr size_t SZ_BF   = (size_t)BM * 512 * 2;           // 54,525,952
constexpr size_t SZ_MAT5 = (size_t)5 * 512 * 512 * 4;      // 5,242,880
constexpr size_t OFF_YB0 = 0;                              // conv ping buffer (bf16 raw y)
constexpr size_t OFF_YB1 = OFF_YB0 + SZ_BF;                // conv pong buffer
constexpr size_t OFF_WT2 = OFF_YB1 + SZ_BF;                // conv weights [4][3][co][ci] bf16
constexpr size_t OFF_X   = OFF_WT2 + 6291456;              // X=0.1A -> A2
constexpr size_t OFF_T1  = OFF_X   + SZ_MAT5;              // P -> A4
constexpr size_t OFF_T2  = OFF_T1  + SZ_MAT5;              // X2 -> A8
constexpr size_t OFF_E   = OFF_T2  + SZ_MAT5;              // E = expm(0.1A) - I
constexpr size_t OFF_MW  = OFF_E   + SZ_MAT5;              // S -> inv(S)  (GJ ping)
constexpr size_t OFF_P2  = OFF_MW  + SZ_MAT5;              // GJ pong, later A16
constexpr size_t OFF_P4  = OFF_P2  + SZ_MAT5;              // A32
constexpr size_t OFF_ROWT= OFF_P4  + SZ_MAT5;              // PIVI pong buffer
constexpr size_t OFF_COLS= OFF_ROWT + 655360;              // [5][512][64] ping
constexpr size_t OFF_COLS2=OFF_COLS + 655360;              // pong
constexpr size_t OFF_PIVI= OFF_COLS2 + 655360;             // [5][64][64] ping
constexpr size_t OFF_PJT = OFF_PIVI + 81920;               // proj_w^T
constexpr size_t OFF_F1T = OFF_PJT + 1048576;              // fc1_w^T
constexpr size_t OFF_G   = OFF_F1T + 1048576;              // g[b][h]
constexpr size_t OFF_POOL= OFF_G   + 1048576;              // pooled[b][o]
constexpr size_t OFF_Z   = OFF_POOL + 1048576;             // fc1 out
constexpr size_t OFF_ST  = OFF_Z   + 1048576;              // fp64 stats [6][2][512]
constexpr size_t OFF_U   = OFF_ST  + 49152;                // u[5][512]
constexpr size_t OFF_SV  = OFF_U   + 10240;                // residual r[5][512]
constexpr size_t OFF_V   = OFF_SV  + 10240;                // V[5][8][512]
constexpr size_t OFF_WV  = OFF_V   + 81920;                // W[5][13][512]
constexpr size_t OFF_S   = OFF_WV  + 133120;               // s[104] + sbar
constexpr size_t WS_NEED = OFF_S + 512;

// ---------------- bf16 helpers ----------------
__device__ __forceinline__ float bf2f(unsigned short u) {
    union { uint32_t i; float f; } x; x.i = (uint32_t)u << 16; return x.f;
}
__device__ __forceinline__ unsigned short f2bf(float f) {
    union { float f; uint32_t i; } x; x.f = f;
    uint32_t r = x.i + 0x7FFFu + ((x.i >> 16) & 1u);
    return (unsigned short)(r >> 16);
}

typedef __bf16 bf16x8 __attribute__((ext_vector_type(8)));
typedef float  f32x4  __attribute__((ext_vector_type(4)));

__device__ __forceinline__ void gld16(const void* g, void* l) {
    __builtin_amdgcn_global_load_lds((const __attribute__((address_space(1))) uint32_t*)g,
                                     (__attribute__((address_space(3))) uint32_t*)l, 16, 0, 0);
}

// BN+ReLU on a packed bf16 pair, repack via v_cvt_pk_bf16_f32 (RNE)
__device__ __forceinline__ uint32_t bnrelu_pk(uint32_t u, float sc0, float sc1, float sh0, float sh1) {
    union { uint32_t i; float f; } a, b;
    a.i = u << 16;            // lo element as f32
    b.i = u & 0xFFFF0000u;    // hi element as f32
    float x0 = fmaxf(fmaf(a.f, sc0, sh0), 0.0f);
    float x1 = fmaxf(fmaf(b.f, sc1, sh1), 0.0f);
    uint32_t r;
    asm volatile("v_cvt_pk_bf16_f32 %0, %1, %2" : "=v"(r) : "v"(x0), "v"(x1));
    return r;
}

// ============ merged: weight prepack + ZOH build + t512 + conv0 ============
__global__ void k_pre(const float* __restrict__ W, unsigned short* __restrict__ Wt2,
                      const float* __restrict__ Aall, float* __restrict__ X, float* __restrict__ MW,
                      float* __restrict__ COLSa, const float* __restrict__ Call, float* __restrict__ WV,
                      const float* __restrict__ pin0, float* __restrict__ pout0,
                      const float* __restrict__ pin1, float* __restrict__ pout1,
                      const float* __restrict__ xin, const float* __restrict__ w0,
                      const float* __restrict__ b0, unsigned short* __restrict__ y0,
                      double* __restrict__ s1g, double* __restrict__ s2g)
{
    __shared__ float tile[64 * 68];
    int bid = blockIdx.x;
    int tid = threadIdx.x;
    if (bid < 2048) {
        // conv weights -> bf16 [l][tap][co][ci], 16B-chunk XOR-swizzled per co row
        int co = bid & 511, l = bid >> 9;
        const float* src = W + (long)(l * 512 + co) * 512 * 3;
        unsigned short* dst = Wt2 + (long)l * 3 * 262144 + ((long)co << 9);
        int v = (co >> 1) & 3;
#pragma unroll
        for (int q = 0; q < 2; ++q) {
            int ci = tid * 2 + q;
            int chunk = (ci >> 3) & 3;
            int di = (ci & ~31) + (((chunk ^ v) & 3) << 3) + (ci & 7);
            float f0 = src[ci * 3 + 0], f1 = src[ci * 3 + 1], f2 = src[ci * 3 + 2];
            dst[di] = f2bf(f0);
            dst[262144 + di] = f2bf(f1);
            dst[524288 + di] = f2bf(f2);
        }
        return;
    }
    if (bid < 7168) {
        // ZOH build: X = 0.1*A, S = A + 0.001 I, COLS p=0, W0=C
        long i = (long)(bid - 2048) * 256 + tid;     // 5*262144 total
        float a = Aall[i];
        X[i] = 0.1f * a;
        int z = (int)(i >> 18);
        int rc = (int)(i & 262143);
        int r = rc >> 9, c = rc & 511;
        float mw = a + ((r == c) ? 0.001f : 0.0f);
        MW[i] = mw;
        if (c < 64) COLSa[(long)z * 32768 + r * 64 + c] = mw;
        if (i < 2560) WV[(i >> 9) * 6656 + (i & 511)] = Call[i];
        return;
    }
    if (bid < 7296) {
        // dual 512x512 transpose (proj_w, fc1_w)
        int id = bid - 7168;
        int bx = id & 7, by = (id >> 3) & 7, zi = id >> 6;
        const float* in = zi ? pin1 : pin0;
        float* outp = zi ? pout1 : pout0;
        for (int it = 0; it < 4; ++it) {
            int s = it * 256 + tid;
            int r = s >> 4, c4 = (s & 15) * 4;
            *(float4*)&tile[r * 68 + c4] = *(const float4*)&in[(long)(bx * 64 + r) * 512 + by * 64 + c4];
        }
        __syncthreads();
        for (int it = 0; it < 4; ++it) {
            int s = it * 256 + tid;
            int r = s >> 4, c4 = (s & 15) * 4;
            float4 v;
            v.x = tile[(c4 + 0) * 68 + r];
            v.y = tile[(c4 + 1) * 68 + r];
            v.z = tile[(c4 + 2) * 68 + r];
            v.w = tile[(c4 + 3) * 68 + r];
            *(float4*)&outp[(long)(by * 64 + r) * 512 + bx * 64 + c4] = v;
        }
        return;
    }
    {
        // conv0 (1->H) + stats, bf16 out
        int id = bid - 7296;
        int b = id & 511;
        int c = (id >> 9) * 256 + tid;
        float w_0 = w0[c * 3 + 0], w_1 = w0[c * 3 + 1], w_2 = w0[c * 3 + 2], bb = b0[c];
        const float* xb = xin + b * 104;
        unsigned short* yb = y0 + (long)b * 104 * 512 + c;
        float xm2 = 0.0f, xm1 = 0.0f;
        float s1 = 0.0f, s2 = 0.0f;
        for (int t = 0; t < 104; ++t) {
            float x0 = xb[t];
            float v = w_0 * xm2 + w_1 * xm1 + w_2 * x0 + bb;
            yb[t * 512] = f2bf(v);
            s1 += v; s2 += v * v;
            xm2 = xm1; xm1 = x0;
        }
        atomicAdd(&s1g[c], (double)s1);
        atomicAdd(&s2g[c], (double)s2);
    }
}

// ================= generic batched 64x64-tile fp32 matmul =================
// mode 0: C = acc
// mode 1: C = acc + 2*aux + I                  (A2 = E*E + 2E + I)
// mode 2: C = acc + aux                        (E = X2*P + X)
// mode 5: C = acc + aux[col]*aux2[0]
// mode 7: C = acc (=X2); Cp = 0.5I + aux/6 + acc/24
// mode 8: C = acc + aux[col]; fp64 column stats -> st1/st2
__global__ __launch_bounds__(256) void k_mm(
    const float* __restrict__ A, long sA, int lda,
    const float* __restrict__ Bm, long sB, int ldb,
    float* __restrict__ C, long sC, int ldc,
    int K, int mode,
    const float* __restrict__ aux, long sAux,
    const float* __restrict__ aux2, float* __restrict__ Cp,
    double* __restrict__ st1, double* __restrict__ st2, int pc)
{
    __shared__ float sm[2 * 32 * 68];
    float* As = sm;
    float* Bs = sm + 32 * 68;
    int z = blockIdx.z;
    A  += (long)z * sA;
    Bm += (long)z * sB;
    C  += (long)z * sC;
    if (aux) aux += (long)z * sAux;
    int m0 = blockIdx.x * 64, n0 = blockIdx.y * 64;
    int tid = threadIdx.x;
    int tx = tid & 15, ty = tid >> 4;
    float acc[4][4] = {};
    for (int k0 = 0; k0 < K; k0 += 32) {
        __syncthreads();
#pragma unroll
        for (int it = 0; it < 2; ++it) {
            int s = it * 256 + tid;
            int mm = s >> 3, k4 = (s & 7) * 4;
            float4 v = *(const float4*)&A[(long)(m0 + mm) * lda + k0 + k4];
            As[(k4 + 0) * 68 + mm] = v.x;
            As[(k4 + 1) * 68 + mm] = v.y;
            As[(k4 + 2) * 68 + mm] = v.z;
            As[(k4 + 3) * 68 + mm] = v.w;
        }
#pragma unroll
        for (int it = 0; it < 2; ++it) {
            int s = it * 256 + tid;
            int kk = s >> 4, n4 = (s & 15) * 4;
            *(float4*)&Bs[kk * 68 + n4] = *(const float4*)&Bm[(long)(k0 + kk) * ldb + n0 + n4];
        }
        __syncthreads();
#pragma unroll 8
        for (int kk = 0; kk < 32; ++kk) {
            float4 a = *(const float4*)&As[kk * 68 + ty * 4];
            float4 b = *(const float4*)&Bs[kk * 68 + tx * 4];
            float av[4] = {a.x, a.y, a.z, a.w};
            float bv[4] = {b.x, b.y, b.z, b.w};
#pragma unroll
            for (int i = 0; i < 4; ++i)
#pragma unroll
                for (int j = 0; j < 4; ++j)
                    acc[i][j] = fmaf(av[i], bv[j], acc[i][j]);
        }
    }
    float sc2 = (mode == 5) ? aux2[0] : 0.0f;
    float cs1[4] = {0, 0, 0, 0}, cs2[4] = {0, 0, 0, 0};
#pragma unroll
    for (int i = 0; i < 4; ++i) {
        int row = m0 + ty * 4 + i;
        int col0 = n0 + tx * 4;
        long base = (long)row * ldc + col0;
        float v[4];
#pragma unroll
        for (int j = 0; j < 4; ++j) v[j] = acc[i][j];
        if (mode == 1) {
            for (int j = 0; j < 4; ++j) {
                int col = col0 + j;
                v[j] = v[j] + 2.0f * aux[(long)row * 512 + col] + ((row == col) ? 1.0f : 0.0f);
            }
        } else if (mode == 2) {
            for (int j = 0; j < 4; ++j)
                v[j] = v[j] + aux[(long)row * 512 + col0 + j];
        } else if (mode == 5) {
            for (int j = 0; j < 4; ++j) v[j] += aux[col0 + j] * sc2;
        } else if (mode == 7) {
            float pv[4];
            for (int j = 0; j < 4; ++j) {
                int col = col0 + j;
                pv[j] = ((row == col) ? 0.5f : 0.0f) + aux[(long)row * 512 + col] * (1.0f / 6.0f)
                        + v[j] * (1.0f / 24.0f);
            }
            *(float4*)&Cp[base] = make_float4(pv[0], pv[1], pv[2], pv[3]);
        } else if (mode == 8) {
            for (int j = 0; j < 4; ++j) {
                v[j] += aux[col0 + j];
                cs1[j] += v[j]; cs2[j] += v[j] * v[j];
            }
        }
        *(float4*)&C[base] = make_float4(v[0], v[1], v[2], v[3]);
    }
    if (mode == 8) {
        __syncthreads();
        float* s1s = sm;           // [16][64]
        float* s2s = sm + 1024;
#pragma unroll
        for (int j = 0; j < 4; ++j) {
            s1s[ty * 64 + tx * 4 + j] = cs1[j];
            s2s[ty * 64 + tx * 4 + j] = cs2[j];
        }
        __syncthreads();
        if (tid < 64) {
            double a = 0.0, b = 0.0;
#pragma unroll
            for (int t = 0; t < 16; ++t) { a += s1s[t * 64 + tid]; b += s2s[t * 64 + tid]; }
            atomicAdd(&st1[n0 + tid], a);
            atomicAdd(&st2[n0 + tid], b);
        }
    }
}

// ====== fused GJ step + next-diag inverse (MWin -> MWout ping-pong; PIVI dbuf) ======
__global__ __launch_bounds__(256) void k_elim3(
    const float* __restrict__ MWin, float* __restrict__ MWout,
    const float* __restrict__ PIVI, float* __restrict__ PIVN,
    const float* __restrict__ COLSc, float* __restrict__ COLSn, int pc, int pcn)
{
    __shared__ float As[64 * 68];
    __shared__ float Rs[64 * 68];
    __shared__ float fv[64];
    __shared__ int perm[64];
    __shared__ int arr[64];
    __shared__ int pividx;
    __shared__ float dv;
    int z = blockIdx.z;
    MWin += (long)z * 262144; MWout += (long)z * 262144;
    PIVI += z * 4096; COLSc += (long)z * 32768; COLSn += (long)z * 32768;
    int m0 = blockIdx.x * 64, n0 = blockIdx.y * 64;
    int tid = threadIdx.x;
    int tx = tid & 15, ty = tid >> 4;

    // ---- phase 1: Rs = ROWT chunk for columns [n0, n0+64)
    if (n0 == pc) {
        for (int it = 0; it < 16; ++it) {
            int idx = it * 256 + tid;
            int r = idx >> 6, c = idx & 63;
            Rs[r * 68 + c] = PIVI[r * 64 + c];
        }
        __syncthreads();
    } else {
        {   // As[k*68 + r] = PIVI[r][k]; Rs[k*68 + c] = MWin[pc+k][n0+c]
            int m = tid >> 2, kb = (tid & 3) * 16;
#pragma unroll
            for (int u = 0; u < 4; ++u) {
                float4 v = *(const float4*)&PIVI[m * 64 + kb + u * 4];
                As[(kb + u * 4 + 0) * 68 + m] = v.x;
                As[(kb + u * 4 + 1) * 68 + m] = v.y;
                As[(kb + u * 4 + 2) * 68 + m] = v.z;
                As[(kb + u * 4 + 3) * 68 + m] = v.w;
            }
            int kr = tid >> 2, cb = (tid & 3) * 16;
#pragma unroll
            for (int u = 0; u < 4; ++u)
                *(float4*)&Rs[kr * 68 + cb + u * 4] =
                    *(const float4*)&MWin[(long)(pc + kr) * 512 + n0 + cb + u * 4];
        }
        __syncthreads();
        float acc1[4][4] = {};
#pragma unroll 8
        for (int kk = 0; kk < 64; ++kk) {
            float4 a = *(const float4*)&As[kk * 68 + ty * 4];
            float4 b = *(const float4*)&Rs[kk * 68 + tx * 4];
            float av[4] = {a.x, a.y, a.z, a.w};
            float bv[4] = {b.x, b.y, b.z, b.w};
#pragma unroll
            for (int i = 0; i < 4; ++i)
#pragma unroll
                for (int j = 0; j < 4; ++j)
                    acc1[i][j] = fmaf(av[i], bv[j], acc1[i][j]);
        }
        __syncthreads();   // all reads of Rs done
#pragma unroll
        for (int i = 0; i < 4; ++i)
#pragma unroll
            for (int j = 0; j < 4; ++j)
                Rs[(ty * 4 + i) * 68 + tx * 4 + j] = acc1[i][j];
        __syncthreads();
    }

    // ---- phase 2
    if (m0 == pc) {
        // pivot row-block: MWout = Rs
        for (int it = 0; it < 16; ++it) {
            int idx = it * 256 + tid;
            int r = idx >> 6, c = idx & 63;
            float v = Rs[r * 68 + c];
            MWout[(long)(pc + r) * 512 + n0 + c] = v;
            if (n0 == pcn) COLSn[(pc + r) * 64 + c] = v;
        }
        return;
    }
    {   // As[k*68 + m] = COLSc[m0+m][k]
        int m = tid >> 2, kb = (tid & 3) * 16;
#pragma unroll
        for (int u = 0; u < 4; ++u) {
            float4 v = *(const float4*)&COLSc[(m0 + m) * 64 + kb + u * 4];
            As[(kb + u * 4 + 0) * 68 + m] = v.x;
            As[(kb + u * 4 + 1) * 68 + m] = v.y;
            As[(kb + u * 4 + 2) * 68 + m] = v.z;
            As[(kb + u * 4 + 3) * 68 + m] = v.w;
        }
    }
    __syncthreads();
    float acc[4][4] = {};
#pragma unroll 8
    for (int kk = 0; kk < 64; ++kk) {
        float4 a = *(const float4*)&As[kk * 68 + ty * 4];
        float4 b = *(const float4*)&Rs[kk * 68 + tx * 4];
        float av[4] = {a.x, a.y, a.z, a.w};
        float bv[4] = {b.x, b.y, b.z, b.w};
#pragma unroll
        for (int i = 0; i < 4; ++i)
#pragma unroll
            for (int j = 0; j < 4; ++j)
                acc[i][j] = fmaf(av[i], bv[j], acc[i][j]);
    }
    bool inP = (n0 == pc);
    float vsav[4][4];
#pragma unroll
    for (int i = 0; i < 4; ++i) {
        int row = m0 + ty * 4 + i;
        int col0 = n0 + tx * 4;
        long base = (long)row * 512 + col0;
        float ov[4] = {0.f, 0.f, 0.f, 0.f};
        if (!inP) {
            float4 oldv = *(const float4*)&MWin[base];
            ov[0] = oldv.x; ov[1] = oldv.y; ov[2] = oldv.z; ov[3] = oldv.w;
        }
        float v[4];
#pragma unroll
        for (int j = 0; j < 4; ++j) { v[j] = ov[j] - acc[i][j]; vsav[i][j] = v[j]; }
        *(float4*)&MWout[base] = make_float4(v[0], v[1], v[2], v[3]);
        if (n0 == pcn)
            *(float4*)&COLSn[row * 64 + (col0 - pcn)] = make_float4(v[0], v[1], v[2], v[3]);
    }

    // ---- phase 3: next-step diag inverse (only the (pcn,pcn) block; skipped when pcn==512)
    if (!(m0 == pcn && n0 == pcn)) return;
    __syncthreads();                      // As free for reuse
    float* mat = As;                      // [64][65]
#pragma unroll
    for (int i = 0; i < 4; ++i)
#pragma unroll
        for (int j = 0; j < 4; ++j)
            mat[(ty * 4 + i) * 65 + tx * 4 + j] = vsav[i][j];
    __syncthreads();
    for (int j = 0; j < 64; ++j) {
        if (tid < 64) {
            float v = (tid >= j) ? fabsf(mat[tid * 65 + j]) : -1.0f;
            int idx = tid;
#pragma unroll
            for (int off = 32; off; off >>= 1) {
                float ov = __shfl_down(v, off);
                int oi = __shfl_down(idx, off);
                if (ov > v) { v = ov; idx = oi; }
            }
            if (tid == 0) pividx = idx;
        }
        __syncthreads();
        int r = pividx;
        if (tid < 64) {
            if (r != j) {
                float tj = mat[j * 65 + tid], tr = mat[r * 65 + tid];
                mat[j * 65 + tid] = tr; mat[r * 65 + tid] = tj;
            }
            if (tid == 0) perm[j] = r;
        }
        __syncthreads();
        if (tid < 64) {
            float piv = mat[j * 65 + j];
            float d = 1.0f / piv;
            fv[tid] = mat[tid * 65 + j];
            mat[j * 65 + tid] = (tid == j) ? d : mat[j * 65 + tid] * d;
            if (tid == 0) dv = d;
        }
        __syncthreads();
        {
            int i = tid & 63, c0 = (tid >> 6) * 16;
            if (i != j) {
                float f = fv[i];
                float dd = dv;
#pragma unroll
                for (int u = 0; u < 16; ++u) {
                    int c = c0 + u;
                    float val = mat[i * 65 + c] - f * mat[j * 65 + c];
                    if (c == j) val = -f * dd;
                    mat[i * 65 + c] = val;
                }
            }
        }
        __syncthreads();
    }
    if (tid == 0) {
        for (int c = 0; c < 64; ++c) arr[c] = c;
        for (int j = 63; j >= 0; --j) { int r = perm[j]; int t = arr[j]; arr[j] = arr[r]; arr[r] = t; }
    }
    __syncthreads();
    float* Pg = PIVN + z * 4096;
    for (int it = 0; it < 16; ++it) {
        int idx = it * 256 + tid;
        int r = idx >> 6, c = idx & 63;
        Pg[r * 64 + c] = mat[r * 65 + arr[c]];
    }
}

// ================= pivoted 64x64 Gauss-Jordan inverse in LDS (initial p=0) =================
__global__ __launch_bounds__(256) void k_inv64(const float* __restrict__ MW, int pblk, float* __restrict__ PIVI)
{
    __shared__ float mat[64 * 65];
    __shared__ float fv[64];
    __shared__ int perm[64];
    __shared__ int arr[64];
    __shared__ int pividx;
    __shared__ float dv;
    int z = blockIdx.x;
    const float* Mg = MW + (long)z * 262144 + (long)pblk * 64 * 512 + pblk * 64;
    int tid = threadIdx.x;
    for (int it = 0; it < 16; ++it) {
        int idx = it * 256 + tid;
        int r = idx >> 6, c = idx & 63;
        mat[r * 65 + c] = Mg[r * 512 + c];
    }
    __syncthreads();
    for (int j = 0; j < 64; ++j) {
        if (tid < 64) {
            float v = (tid >= j) ? fabsf(mat[tid * 65 + j]) : -1.0f;
            int idx = tid;
#pragma unroll
            for (int off = 32; off; off >>= 1) {
                float ov = __shfl_down(v, off);
                int oi = __shfl_down(idx, off);
                if (ov > v) { v = ov; idx = oi; }
            }
            if (tid == 0) pividx = idx;
        }
        __syncthreads();
        int r = pividx;
        if (tid < 64) {
            if (r != j) {
                float tj = mat[j * 65 + tid], tr = mat[r * 65 + tid];
                mat[j * 65 + tid] = tr; mat[r * 65 + tid] = tj;
            }
            if (tid == 0) perm[j] = r;
        }
        __syncthreads();
        if (tid < 64) {
            float piv = mat[j * 65 + j];
            float d = 1.0f / piv;
            fv[tid] = mat[tid * 65 + j];
            mat[j * 65 + tid] = (tid == j) ? d : mat[j * 65 + tid] * d;
            if (tid == 0) dv = d;
        }
        __syncthreads();
        {
            int i = tid & 63, c0 = (tid >> 6) * 16;
            if (i != j) {
                float f = fv[i];
                float dd = dv;
#pragma unroll
                for (int u = 0; u < 16; ++u) {
                    int c = c0 + u;
                    float val = mat[i * 65 + c] - f * mat[j * 65 + c];
                    if (c == j) val = -f * dd;
                    mat[i * 65 + c] = val;
                }
            }
        }
        __syncthreads();
    }
    if (tid == 0) {
        for (int c = 0; c < 64; ++c) arr[c] = c;
        for (int j = 63; j >= 0; --j) { int r = perm[j]; int t = arr[j]; arr[j] = arr[r]; arr[r] = t; }
    }
    __syncthreads();
    float* Pg = PIVI + z * 4096;
    for (int it = 0; it < 16; ++it) {
        int idx = it * 256 + tid;
        int r = idx >> 6, c = idx & 63;
        Pg[r * 64 + c] = mat[r * 65 + arr[c]];
    }
}

// ================= batched matvec: y = alpha*(A x) + beta*x (B_bar path) =================
__global__ void k_matvecA(const float* __restrict__ A, long sA,
                          const float* __restrict__ x, long sx,
                          float* __restrict__ y, long sy,
                          const float* __restrict__ sub, long ssub,
                          float alpha, float beta, int accum)
{
    int row = blockIdx.x, z = blockIdx.y, lane = threadIdx.x;
    A += (long)z * sA; x += (long)z * sx; y += (long)z * sy;
    if (sub) sub += (long)z * ssub;
    const float* ar = A + (long)row * 512;
    double acc = 0.0;
#pragma unroll
    for (int m = 0; m < 8; ++m) {
        int k = lane + m * 64;
        acc += (double)ar[k] * (double)x[k];
    }
    for (int off = 32; off; off >>= 1) acc += __shfl_down(acc, off);
    if (lane == 0) {
        float val = alpha * (float)acc + beta * x[row];
        if (sub) val = sub[row] - val;
        if (accum) y[row] += val; else y[row] = val;
    }
}

// ================= merged V/W chain multi-task matvec =================
struct VWT { long a[8]; long x[8]; long y[8]; float al[8]; float be[8]; int ty[8]; };
__global__ void k_vw(const char* __restrict__ ws, VWT T)
{
    int g = blockIdx.x, z = blockIdx.y, t = blockIdx.z;
    int lane = threadIdx.x;
    const float* A = (const float*)(ws + T.a[t]) + (long)z * 262144;
    int ty = T.ty[t];
    long vs = ty ? 6656 : 4096;
    const float* x = (const float*)(ws + T.x[t]) + (long)z * vs;
    float* yv = (float*)(ws + T.y[t]) + (long)z * vs;
    if (ty == 0) {
        float xm[8];
#pragma unroll
        for (int m = 0; m < 8; ++m) xm[m] = x[lane + m * 64];
        float alpha = T.al[t], beta = T.be[t];
        for (int r0 = 0; r0 < 64; ++r0) {
            int row = g * 64 + r0;
            const float* ar = A + (long)row * 512;
            double acc = 0.0;
#pragma unroll
            for (int m = 0; m < 8; ++m) acc += (double)ar[lane + m * 64] * (double)xm[m];
            for (int off = 32; off; off >>= 1) acc += __shfl_down(acc, off);
            if (lane == 0) yv[row] = alpha * (float)acc + beta * x[row];
        }
    } else {
        __shared__ float xl[512];
#pragma unroll
        for (int m = 0; m < 8; ++m) xl[lane + m * 64] = x[lane + m * 64];
        __syncthreads();
        int c = g * 64 + lane;
        double acc = 0.0;
#pragma unroll 8
        for (int j = 0; j < 512; ++j) acc += (double)A[(long)j * 512 + c] * (double)xl[j];
        yv[c] = (float)acc;
    }
}

// ================= MFMA conv GEMM, 128x128 tile, 4 blocks/CU, tap-fused ====
// Extra block (blockIdx.x==416, y==0, l==1 only) runs the terms+s-kernel.
__global__ __launch_bounds__(256, 4) void k_convm(
    const unsigned short* __restrict__ act,      // raw y of previous layer
    const unsigned short* __restrict__ Wt2,      // layer base [3][512][512] (chunk-swizzled)
    const float* __restrict__ bias,
    const double* __restrict__ STin,             // prev layer stats [2][512]
    const float* __restrict__ gam, const float* __restrict__ bet,
    unsigned short* __restrict__ yout,
    double* __restrict__ s1g, double* __restrict__ s2g,
    const float* __restrict__ WVt, const float* __restrict__ Vt, float* __restrict__ SVECt)
{
    __shared__ __align__(16) unsigned short As[130 * 32];     // 8320 B
    __shared__ __align__(16) unsigned short Bs[3 * 128 * 32]; // 24576 B
    __shared__ float SCs[512];
    __shared__ float SHs[512];
    __shared__ float invk[5];
    __shared__ float redk[2];
    int tid = threadIdx.x;
    if (blockIdx.x == 416) {
        if (blockIdx.y != 0 || WVt == nullptr) return;
        // ---- terms + s-kernel (256-thread variant)
        float* tl = (float*)As;
        for (int t = tid; t < 520; t += 256) {
            int z = t / 104, d = t - z * 104;
            int j = d >> 3, i = d & 7;
            const float* wp = WVt + z * 6656 + j * 512;
            const float* vp = Vt + z * 4096 + i * 512;
            float acc = 0.0f;
#pragma unroll 8
            for (int k = 0; k < 512; ++k) acc += wp[k] * vp[k];
            tl[t] = acc;
        }
        __syncthreads();
        int lane = tid & 63;
        for (int g = tid >> 6; g < 5; g += 4) {
            float a = tl[g * 104 + lane]; a = a * a;
            if (lane < 40) { float b = tl[g * 104 + 64 + lane]; a += b * b; }
#pragma unroll
            for (int off = 32; off; off >>= 1) a += __shfl_down(a, off);
            if (lane == 0) invk[g] = 1.0f / (sqrtf(a) + 1e-6f);
        }
        __syncthreads();
        float s = 0.0f;
        if (tid < 104) {
            s = 1.0f;
            for (int l = 0; l < 5; ++l) s *= tl[l * 104 + (103 - tid)] * invk[l];
            SVECt[tid] = s;
        }
        if (tid < 128) {
            float v = (tid < 104) ? s : 0.0f;
#pragma unroll
            for (int off = 32; off; off >>= 1) v += __shfl_down(v, off);
            if ((tid & 63) == 0) redk[tid >> 6] = v;
        }
        __syncthreads();
        if (tid == 0) SVECt[104] = (redk[0] + redk[1]) * (1.0f / 104.0f);
        return;
    }
    int m0 = blockIdx.x * 128, co0 = blockIdx.y * 128;
    int w = tid >> 6, lane = tid & 63;
    int wr = (w >> 1) * 64, wc = (w & 1) * 64;
    int fr = lane & 15, quad = lane >> 4;

    // BN scale/shift tables (fp64 stats -> f32)
    const double invN = 1.0 / (double)BM;
    for (int c = tid; c < 512; c += 256) {
        double mn = STin[c] * invN;
        double var = STin[512 + c] * invN - mn * mn;
        double rs = 1.0 / sqrt(var + (double)BN_EPS);
        double scd = (double)gam[c] * rs;
        SCs[c] = (float)scd;
        SHs[c] = (float)((double)bet[c] - mn * scd);
    }

    bool valid[4][3];
#pragma unroll
    for (int i = 0; i < 4; ++i) {
        int R = m0 + wr + i * 16 + fr;
        int t = R % 104;
#pragma unroll
        for (int tau = 0; tau < 3; ++tau) valid[i][tau] = (t + tau >= 2);
    }

    // precomputed swizzled LDS fragment addresses (ushort indices)
    int aoff[4][3];
#pragma unroll
    for (int i = 0; i < 4; ++i)
#pragma unroll
        for (int tau = 0; tau < 3; ++tau) {
            int r = wr + i * 16 + fr + tau;
            aoff[i][tau] = r * 32 + (((quad ^ (r >> 1)) & 3) << 3);
        }
    int boff[4];
#pragma unroll
    for (int j = 0; j < 4; ++j) {
        int rb = wc + j * 16 + fr;
        boff[j] = rb * 32 + (((quad ^ (rb >> 1)) & 3) << 3);
    }

    // A staging pointers (rows m0-2 .. m0+129 of act)
    int ka = (tid & 3) * 8;
    int g0 = m0 - 2 + (tid >> 2); if (g0 < 0) g0 = 0;
    int g1 = m0 + 62 + (tid >> 2);
    int g2 = m0 + 126 + (tid >> 2);
    const unsigned short* pa0 = act + (long)g0 * 512 + ka;
    const unsigned short* pa1 = act + (long)g1 * 512 + ka;
    const unsigned short* pa2 = act + (long)g2 * 512 + ka;
    // A staging write base (chunk-XOR swizzle)
    int wbase = (tid >> 2) * 32 + ((((tid & 3) ^ (tid >> 3)) & 3) << 3);
    // B staging global base (swizzle baked into Wt2 by k_pre)
    const unsigned short* pbB = Wt2 + ((long)(co0 + (tid >> 2)) << 9) + ka;

    f32x4 zero4 = {0.f, 0.f, 0.f, 0.f};
    f32x4 acc[4][4];
#pragma unroll
    for (int i = 0; i < 4; ++i)
#pragma unroll
        for (int j = 0; j < 4; ++j) acc[i][j] = zero4;
    bf16x8 zer = {0, 0, 0, 0, 0, 0, 0, 0};

#pragma unroll 1
    for (int s = 0; s < 16; ++s) {
        int ci0 = s * 32;
        __syncthreads();
        // A: issue VGPR loads first
        uint4 va0 = *(const uint4*)(pa0 + ci0);
        uint4 va1 = *(const uint4*)(pa1 + ci0);
        uint4 va2;
        if (tid < 8) va2 = *(const uint4*)(pa2 + ci0);
        // B: 6 async global->LDS (24 KB)
#pragma unroll
        for (int tau = 0; tau < 3; ++tau)
#pragma unroll
            for (int it = 0; it < 2; ++it)
                gld16(pbB + tau * 262144 + it * 32768 + ci0, &Bs[(tau * 2 + it) * 2048 + tid * 8]);
        // A: BN+ReLU + cvt_pk repack + swizzled ds_write
        int cb = ci0 + ka;
        float4 s0 = *(const float4*)&SCs[cb], s1v = *(const float4*)&SCs[cb + 4];
        float4 h0 = *(const float4*)&SHs[cb], h1v = *(const float4*)&SHs[cb + 4];
        {
            uint4 pk;
            pk.x = bnrelu_pk(va0.x, s0.x, s0.y, h0.x, h0.y);
            pk.y = bnrelu_pk(va0.y, s0.z, s0.w, h0.z, h0.w);
            pk.z = bnrelu_pk(va0.z, s1v.x, s1v.y, h1v.x, h1v.y);
            pk.w = bnrelu_pk(va0.w, s1v.z, s1v.w, h1v.z, h1v.w);
            *(uint4*)&As[wbase] = pk;
            pk.x = bnrelu_pk(va1.x, s0.x, s0.y, h0.x, h0.y);
            pk.y = bnrelu_pk(va1.y, s0.z, s0.w, h0.z, h0.w);
            pk.z = bnrelu_pk(va1.z, s1v.x, s1v.y, h1v.x, h1v.y);
            pk.w = bnrelu_pk(va1.w, s1v.z, s1v.w, h1v.z, h1v.w);
            *(uint4*)&As[wbase + 2048] = pk;
            if (tid < 8) {
                pk.x = bnrelu_pk(va2.x, s0.x, s0.y, h0.x, h0.y);
                pk.y = bnrelu_pk(va2.y, s0.z, s0.w, h0.z, h0.w);
                pk.z = bnrelu_pk(va2.z, s1v.x, s1v.y, h1v.x, h1v.y);
                pk.w = bnrelu_pk(va2.w, s1v.z, s1v.w, h1v.z, h1v.w);
                *(uint4*)&As[wbase + 4096] = pk;
            }
        }
        __syncthreads();
#pragma unroll
        for (int tau = 0; tau < 3; ++tau) {
            bf16x8 af[4];
#pragma unroll
            for (int i = 0; i < 4; ++i) {
                bf16x8 raw = *(const bf16x8*)&As[aoff[i][tau]];
                af[i] = valid[i][tau] ? raw : zer;
            }
            bf16x8 bfr[4];
#pragma unroll
            for (int j = 0; j < 4; ++j)
                bfr[j] = *(const bf16x8*)&Bs[tau * 4096 + boff[j]];
#pragma unroll
            for (int i = 0; i < 4; ++i)
#pragma unroll
                for (int j = 0; j < 4; ++j)
                    acc[i][j] = __builtin_amdgcn_mfma_f32_16x16x32_bf16(af[i], bfr[j], acc[i][j], 0, 0, 0);
        }
    }
    // epilogue: bias, bf16 store, per-channel stats
    float bcol[4], s1[4] = {0, 0, 0, 0}, s2[4] = {0, 0, 0, 0};
#pragma unroll
    for (int jt = 0; jt < 4; ++jt) bcol[jt] = bias[co0 + wc + jt * 16 + fr];
#pragma unroll
    for (int i = 0; i < 4; ++i) {
        int rbase = m0 + wr + i * 16 + quad * 4;
#pragma unroll
        for (int jt = 0; jt < 4; ++jt) {
            int col = co0 + wc + jt * 16 + fr;
#pragma unroll
            for (int r = 0; r < 4; ++r) {
                float v = acc[i][jt][r] + bcol[jt];
                yout[(long)(rbase + r) * 512 + col] = f2bf(v);
                s1[jt] += v; s2[jt] += v * v;
            }
        }
    }
#pragma unroll
    for (int jt = 0; jt < 4; ++jt) {
        s1[jt] += __shfl_xor(s1[jt], 16); s1[jt] += __shfl_xor(s1[jt], 32);
        s2[jt] += __shfl_xor(s2[jt], 16); s2[jt] += __shfl_xor(s2[jt], 32);
    }
    __syncthreads();
    float* st = (float*)As;   // [4][64] x2 = 2 KB scratch
    if (lane < 16) {
#pragma unroll
        for (int jt = 0; jt < 4; ++jt) {
            st[w * 64 + jt * 16 + lane] = s1[jt];
            st[256 + w * 64 + jt * 16 + lane] = s2[jt];
        }
    }
    __syncthreads();
    if (tid < 128) {
        int w0 = tid >> 6, cl = tid & 63;
        float a = st[w0 * 64 + cl] + st[(w0 + 2) * 64 + cl];
        float b = st[256 + w0 * 64 + cl] + st[256 + (w0 + 2) * 64 + cl];
        atomicAdd(&s1g[co0 + tid], (double)a);
        atomicAdd(&s2g[co0 + tid], (double)b);
    }
}

// ================= pool: g[b][h] = (1/M) sum_t s[t]*(relu(bn4(y4)) + pe[t][h]) =================
__global__ void k_pool(const unsigned short* __restrict__ y4, const double* __restrict__ ST4,
                       const float* __restrict__ gam, const float* __restrict__ bet,
                       const float* __restrict__ svec, float* __restrict__ g)
{
    __shared__ float sl[104];
    int b = blockIdx.x;
    int c = blockIdx.y * 256 + threadIdx.x;
    if (threadIdx.x < 104) sl[threadIdx.x] = svec[threadIdx.x];
    __syncthreads();
    const double invN = 1.0 / (double)BM;
    double mn = ST4[c] * invN;
    double var = ST4[512 + c] * invN - mn * mn;
    double rs = 1.0 / sqrt(var + (double)BN_EPS);
    double scd = (double)gam[c] * rs;
    float sc = (float)scd, sh = (float)((double)bet[c] - mn * scd);
    int he = c & ~1;
    float div = expf((float)he * (-0.017988946039015984f));   // -ln(10000)/512
    float acc = 0.0f;
    const unsigned short* yb = y4 + (long)b * 104 * 512 + c;
    for (int t = 0; t < 104; ++t) {
        float v = bf2f(yb[t * 512]);
        float hn = fmaxf(fmaf(v, sc, sh), 0.0f);
        float arg = (float)t * div;
        float pe = (c & 1) ? cosf(arg) : sinf(arg);
        acc += sl[t] * (hn + pe);
    }
    g[(long)b * 512 + c] = acc * (1.0f / 104.0f);
}

// BN(batch) -> exact GELU -> fc2
__global__ __launch_bounds__(256) void k_final(const float* __restrict__ zin, const double* __restrict__ st,
                                               const float* __restrict__ gam, const float* __restrict__ bet,
                                               const float* __restrict__ w2, const float* __restrict__ b2,
                                               float* __restrict__ outp)
{
    __shared__ float red[256];
    int b = blockIdx.x, tid = threadIdx.x;
    int oo[2] = { tid, tid + 256 };
    float gv[2];
#pragma unroll
    for (int q = 0; q < 2; ++q) {
        int o = oo[q];
        double m = st[o] * (1.0 / 512.0);
        double var = st[512 + o] * (1.0 / 512.0) - m * m;
        double rs = 1.0 / sqrt(var + (double)BN_EPS);
        float xn = (float)(((double)zin[(long)b * 512 + o] - m) * rs * (double)gam[o] + (double)bet[o]);
        gv[q] = 0.5f * xn * (1.0f + erff(xn * 0.70710678118654752f));
    }
    for (int n = 0; n < 5; ++n) {
        float p = gv[0] * w2[n * 512 + oo[0]] + gv[1] * w2[n * 512 + oo[1]];
        red[tid] = p;
        __syncthreads();
        for (int off = 128; off; off >>= 1) { if (tid < off) red[tid] += red[tid + off]; __syncthreads(); }
        if (tid == 0) outp[b * 5 + n] = red[0] + b2[n];
        __syncthreads();
    }
}

// ===================== host side =====================
static void mm(hipStream_t s, int Mt, int Nt, int z,
               const float* A, long sA, int lda,
               const float* B, long sB, int ldb,
               float* C, long sC, int ldc,
               int K, int mode,
               const float* aux = nullptr, long sAux = 0, const float* aux2 = nullptr,
               float* Cp = nullptr, double* st1 = nullptr, double* st2 = nullptr, int pc = 0)
{
    dim3 g(Mt, Nt, z);
    k_mm<<<g, 256, 0, s>>>(A, sA, lda, B, sB, ldb, C, sC, ldc, K, mode, aux, sAux, aux2, Cp, st1, st2, pc);
}

extern "C" void kernel_launch(void* const* d_in, const int* in_sizes, int n_in,
                              void* d_out, int out_size, void* d_ws, size_t ws_size,
                              hipStream_t stream)
{
    (void)in_sizes; (void)n_in; (void)out_size;
    const float* x       = (const float*)d_in[0];
    const float* conv_w0 = (const float*)d_in[1];
    const float* conv_b0 = (const float*)d_in[2];
    const float* conv_w  = (const float*)d_in[3];
    const float* conv_b  = (const float*)d_in[4];
    const float* bn_g    = (const float*)d_in[5];
    const float* bn_b    = (const float*)d_in[6];
    const float* proj_w  = (const float*)d_in[7];
    const float* proj_b  = (const float*)d_in[8];
    const float* A_all   = (const float*)d_in[9];
    const float* B_all   = (const float*)d_in[10];
    const float* C_all   = (const float*)d_in[11];
    const float* fc1_w   = (const float*)d_in[12];
    const float* fc1_b   = (const float*)d_in[13];
    const float* fbn_g   = (const float*)d_in[14];
    const float* fbn_b   = (const float*)d_in[15];
    const float* fc2_w   = (const float*)d_in[16];
    const float* fc2_b   = (const float*)d_in[17];
    float* outp = (float*)d_out;
    char* ws = (char*)d_ws;
    if (ws_size < WS_NEED) { printf("ws too small: %zu < %zu\n", ws_size, WS_NEED); return; }

    unsigned short* YB0 = (unsigned short*)(ws + OFF_YB0);
    unsigned short* YB1 = (unsigned short*)(ws + OFF_YB1);
    unsigned short* WT2 = (unsigned short*)(ws + OFF_WT2);
    float* Xb   = (float*)(ws + OFF_X);
    float* T1   = (float*)(ws + OFF_T1);
    float* T2   = (float*)(ws + OFF_T2);
    float* Eb   = (float*)(ws + OFF_E);
    float* MW   = (float*)(ws + OFF_MW);
    float* P2   = (float*)(ws + OFF_P2);
    float* P4   = (float*)(ws + OFF_P4);
    float* COLS1= (float*)(ws + OFF_COLS);
    float* COLS2= (float*)(ws + OFF_COLS2);
    float* PIVA = (float*)(ws + OFF_PIVI);
    float* PIVB = (float*)(ws + OFF_ROWT);
    float* PJT  = (float*)(ws + OFF_PJT);
    float* F1T  = (float*)(ws + OFF_F1T);
    float* G    = (float*)(ws + OFF_G);
    float* POOL = (float*)(ws + OFF_POOL);
    float* Zb   = (float*)(ws + OFF_Z);
    double* ST  = (double*)(ws + OFF_ST);
    float* U    = (float*)(ws + OFF_U);
    float* SV   = (float*)(ws + OFF_SV);
    float* V    = (float*)(ws + OFF_V);
    float* WV   = (float*)(ws + OFF_WV);
    float* SVEC = (float*)(ws + OFF_S);

    const long SM = 262144;
    hipMemsetAsync(ws + OFF_ST, 0, 49152, stream);

    // ---- merged prepack + build + t512 + conv0 ----
    k_pre<<<8320, 256, 0, stream>>>(conv_w, WT2, A_all, Xb, MW, COLS1, C_all, WV,
                                    proj_w, PJT, fc1_w, F1T,
                                    x, conv_w0, conv_b0, YB0, ST, ST + 512);

    // ---- blocked Gauss-Jordan inverse of S (MW<->P2 ping-pong; PIVI double-buffered) ----
    {
        float* MB[2]  = { MW, P2 };
        float* PB[2]  = { PIVA, PIVB };
        k_inv64<<<5, 256, 0, stream>>>(MW, 0, PB[0]);
        for (int p = 0; p < 8; ++p) {
            int pc = p * 64;
            float* Cc = (p & 1) ? COLS2 : COLS1;
            float* Cn = (p & 1) ? COLS1 : COLS2;
            k_elim3<<<dim3(8, 8, 5), 256, 0, stream>>>(MB[p & 1], MB[(p + 1) & 1],
                                                       PB[p & 1], PB[(p + 1) & 1],
                                                       Cc, Cn, pc, pc + 64);
        }
    }
    // ---- expm chain: X2(+P), E, A2, A4, A8, A16, A32 ----
    mm(stream, 8, 8, 5, Xb, SM, 512, Xb, SM, 512, T2, SM, 512, 512, 7, Xb, SM, nullptr, T1);
    mm(stream, 8, 8, 5, T2, SM, 512, T1, SM, 512, Eb, SM, 512, 512, 2, Xb, SM);
    mm(stream, 8, 8, 5, Eb, SM, 512, Eb, SM, 512, Xb, SM, 512, 512, 1, Eb, SM);
    mm(stream, 8, 8, 5, Xb, SM, 512, Xb, SM, 512, T1, SM, 512, 512, 0);
    mm(stream, 8, 8, 5, T1, SM, 512, T1, SM, 512, T2, SM, 512, 512, 0);
    mm(stream, 8, 8, 5, T2, SM, 512, T2, SM, 512, P2, SM, 512, 512, 0);
    mm(stream, 8, 8, 5, P2, SM, 512, P2, SM, 512, P4, SM, 512, 512, 0);
    // ---- B_bar with one fp64-residual refinement step (max-parallel matvecs) ----
    k_matvecA<<<dim3(512, 5), 64, 0, stream>>>(Eb, SM, B_all, 512, U, 512, nullptr, 0, 0.1f, 0.0f, 0);
    k_matvecA<<<dim3(512, 5), 64, 0, stream>>>(MW, SM, U, 512, V, 4096, nullptr, 0, 1.0f, 0.0f, 0);
    k_matvecA<<<dim3(512, 5), 64, 0, stream>>>(A_all, SM, V, 4096, SV, 512, U, 512, 1.0f, 0.001f, 0);
    k_matvecA<<<dim3(512, 5), 64, 0, stream>>>(MW, SM, SV, 512, V, 4096, nullptr, 0, 1.0f, 0.0f, 1);
    // ---- merged V/W chains ----
    auto Voff = [](int i) { return (long)(OFF_V + (size_t)i * 2048); };
    auto Woff = [](int j) { return (long)(OFF_WV + (size_t)j * 2048); };
    {
        VWT T = {};
        T.a[0] = OFF_E;  T.x[0] = Voff(0); T.y[0] = Voff(1); T.al[0] = 1; T.be[0] = 1; T.ty[0] = 0;
        T.a[1] = OFF_T2; T.x[1] = Woff(0); T.y[1] = Woff(1); T.ty[1] = 1;
        k_vw<<<dim3(8, 5, 2), 64, 0, stream>>>(ws, T);
    }
    {
        VWT T = {};
        T.a[0] = OFF_X;  T.x[0] = Voff(0); T.y[0] = Voff(2); T.al[0] = 1; T.ty[0] = 0;
        T.a[1] = OFF_X;  T.x[1] = Voff(1); T.y[1] = Voff(3); T.al[1] = 1; T.ty[1] = 0;
        T.a[2] = OFF_P2; T.x[2] = Woff(0); T.y[2] = Woff(2); T.ty[2] = 1;
        T.a[3] = OFF_P2; T.x[3] = Woff(1); T.y[3] = Woff(3); T.ty[3] = 1;
        k_vw<<<dim3(8, 5, 4), 64, 0, stream>>>(ws, T);
    }
    {
        VWT T = {};
        for (int i = 0; i < 4; ++i) {
            T.a[i] = OFF_T1; T.x[i] = Voff(i); T.y[i] = Voff(4 + i); T.al[i] = 1; T.ty[i] = 0;
            T.a[4 + i] = OFF_P4; T.x[4 + i] = Woff(i); T.y[4 + i] = Woff(4 + i); T.ty[4 + i] = 1;
        }
        k_vw<<<dim3(8, 5, 8), 64, 0, stream>>>(ws, T);
    }
    {
        VWT T = {};
        for (int i = 0; i < 4; ++i) {
            T.a[i] = OFF_P4; T.x[i] = Woff(4 + i); T.y[i] = Woff(8 + i); T.ty[i] = 1;
        }
        k_vw<<<dim3(8, 5, 4), 64, 0, stream>>>(ws, T);
    }
    {
        VWT T = {};
        T.a[0] = OFF_P4; T.x[0] = Woff(8); T.y[0] = Woff(12); T.ty[0] = 1;
        k_vw<<<dim3(8, 5, 1), 64, 0, stream>>>(ws, T);
    }

    // ---- conv chain (128x128 tile, 4 blocks/CU; termsk rides as extra block in l=1) ----
    for (int l = 1; l <= 4; ++l) {
        unsigned short* inb  = (l & 1) ? YB0 : YB1;
        unsigned short* outb = (l & 1) ? YB1 : YB0;
        dim3 grid(l == 1 ? 417 : 416, 4);
        k_convm<<<grid, 256, 0, stream>>>(inb, WT2 + (size_t)(l - 1) * 3 * 262144,
                                          conv_b + (l - 1) * 512,
                                          ST + (l - 1) * 1024, bn_g + (l - 1) * 512, bn_b + (l - 1) * 512,
                                          outb, ST + l * 1024, ST + l * 1024 + 512,
                                          (l == 1) ? WV : nullptr, V, SVEC);
    }
    k_pool<<<dim3(512, 2), 256, 0, stream>>>(YB0, ST + 4 * 1024, bn_g + 4 * 512, bn_b + 4 * 512, SVEC, G);

    // ---- head ----
    mm(stream, 8, 8, 1, G, 0, 512, PJT, 0, 512, POOL, 0, 512, 512, 5, proj_b, 0, SVEC + 104);
    mm(stream, 8, 8, 1, POOL, 0, 512, F1T, 0, 512, Zb, 0, 512, 512, 8, fc1_b, 0, nullptr, nullptr,
       ST + 5 * 1024, ST + 5 * 1024 + 512);
    k_final<<<512, 256, 0, stream>>>(Zb, ST + 5 * 1024, fbn_g, fbn_b, fc2_w, fc2_b, outp);
}